// Round 6
// baseline (2224.680 us; speedup 1.0000x reference)
//
#include <hip/hip_runtime.h>

// Problem constants (fixed by setup_inputs)
#define BB 32
#define NN 64
#define TT 11
#define FF 4
#define KK 2
#define EE 4032      // N*(N-1)
#define NSTEP 10

typedef _Float16 f16x8 __attribute__((ext_vector_type(8)));
typedef float    f32x4v __attribute__((ext_vector_type(4)));

// ---- fused kernel LDS ----
// phase C: u dbuf [2][64][512B XOR-swz] 64K | vbh dbuf [2][8][256]f16 8K |
//          y [64][4]f32 1K | wgt [2][8][64]f32 4K | agg [8][256]f32 8K
// phase D reuses the u region as a Wo chunk double-buffer [2][32][256]f32 (2x32K);
//          aug/P1/P2 live after AGG.
#define OFF_U0   0
#define OFF_VB   65536
#define OFF_Y    73728
#define OFF_WGT  74752
#define OFF_AGG  78848
#define OFF_AUG  87040      // [8][264] f32 = 8448
#define OFF_P1   95488      // [8][256] f32 = 8192
#define OFF_P2   103680     // [8][256] f32 = 8192
#define SMEM2    111872

__device__ __forceinline__ float scrub(float v) {
    return fminf(fmaxf(v, -3.0e4f), 3.0e4f);   // inactive when correct (|x| <~ 600)
}

__device__ __forceinline__ float load_dt(const float* ts, const void* scp, int step) {
    float t0 = ts[step], t1 = ts[step + 1];
    int w = ((const int*)scp)[0];
    float scl;
    if (w > 0 && w < 1000000) scl = (float)w;            // int32 (live path)
    else {
        float f = __int_as_float(w);
        scl = (f > 0.5f && f < 1.0e6f) ? f : 10.0f;
    }
    return (t1 - t0) / scl;
}

typedef __attribute__((address_space(1))) const unsigned int glb_u32;
typedef __attribute__((address_space(3))) unsigned int lds_u32;
__device__ __forceinline__ void gload_lds16(const void* g, void* l) {
    __builtin_amdgcn_global_load_lds((glb_u32*)g, (lds_u32*)l, 16, 0, 0);
}

// Stage 32 rows x 256 cols f32 (32 KiB) of a weight matrix into LDS via async DMA.
// LDS dest must be wave-uniform (HW adds lane*16); global src is per-lane.
__device__ __forceinline__ void stage32rows(const float* __restrict__ src, char* dstbase, int tid) {
    const int wn = tid >> 6;
    #pragma unroll
    for (int it = 0; it < 4; ++it)
        gload_lds16((const char*)src + (size_t)(it * 512 + tid) * 16,
                    dstbase + it * 8192 + wn * 1024);
}

// u-build (512 thr): u[s][h] = sum_f y_s[f] * W1send[k][f][h], f16, XOR-swizzled rows.
__device__ __forceinline__ void build_uk(char* smem, int buf, int k, int tid,
    const float* __restrict__ W1g, const float* smY)
{
    int hg = tid & 31, sb = tid >> 5;          // sb = 0..15
    const float* w1p = W1g + k * 2048 + hg * 8;
    f32x4v wA[4], wB[4];
    #pragma unroll
    for (int f = 0; f < 4; ++f) {
        wA[f] = *(const f32x4v*)(w1p + f * 256);
        wB[f] = *(const f32x4v*)(w1p + f * 256 + 4);
    }
    const int swz = (hg * 16) ^ ((sb & 7) << 4);   // s&7 == sb&7 (it*16 ≡ 0 mod 8)
    char* ub = smem + OFF_U0 + buf * 32768;
    #pragma unroll
    for (int it = 0; it < 4; ++it) {
        int s = sb + it * 16;
        f32x4v yv = *(const f32x4v*)(smY + s * 4);
        f16x8 uv;
        #pragma unroll
        for (int e = 0; e < 4; ++e) {
            float vA = yv[0]*wA[0][e] + yv[1]*wA[1][e] + yv[2]*wA[2][e] + yv[3]*wA[3][e];
            float vB = yv[0]*wB[0][e] + yv[1]*wB[1][e] + yv[2]*wB[2][e] + yv[3]*wB[3][e];
            uv[e]     = (_Float16)vA;
            uv[e + 4] = (_Float16)vB;
        }
        *(f16x8*)(ub + s * 512 + swz) = uv;
    }
}

// vbh[buf][rv][h] = f16( b1 + sum_f y_recv[f] * W1recv[k][f][h] ), rv = 0..7
__device__ __forceinline__ void build_vbh(_Float16* smVBH, int buf, int k, int tid, int r0,
    const float* __restrict__ W1g, const float* __restrict__ b1g, const float* smY)
{
    #pragma unroll
    for (int it = 0; it < 4; ++it) {
        int i = tid + it * 512;
        int rv = i >> 8, h = i & 255;
        float acch = b1g[k * 256 + h];
        #pragma unroll
        for (int f = 0; f < 4; ++f)
            acch += smY[(r0 + rv) * 4 + f] * W1g[k * 2048 + (4 + f) * 256 + h];
        smVBH[buf * 2048 + i] = (_Float16)acch;
    }
}

// One GEMM pass: 128 rows (pair p: 2 receivers x 64 senders) x 64 cols (quarter q),
// one k. Accumulates relu(acc)*w into smAgg (k==0 stores, k==1 adds).
__device__ __forceinline__ void gemm_pass(char* smem, int buf, int k, int q, int p,
    const _Float16* __restrict__ W2F, const float* __restrict__ b2g,
    const float* smWgt, float* smAgg,
    int lane, int ln15, int lg, const int* uoff, int xm6)
{
    const _Float16* smVBH = (const _Float16*)(smem + OFF_VB);

    float bv[4];
    #pragma unroll
    for (int ni = 0; ni < 4; ++ni)
        bv[ni] = b2g[k * 256 + q * 64 + ni * 16 + ln15];

    f32x4v acc[8][4];         // b2 folded into init
    #pragma unroll
    for (int mi = 0; mi < 8; ++mi)
        #pragma unroll
        for (int ni = 0; ni < 4; ++ni)
            acc[mi][ni] = (f32x4v){bv[ni], bv[ni], bv[ni], bv[ni]};

    const _Float16* bbase = W2F + ((size_t)((k * 16 + q * 4) * 8)) * 512 + lane * 8;
    const char* ubase = smem + OFF_U0 + buf * 32768;
    const char* vbase = (const char*)(smVBH + buf * 2048 + p * 512);  // rows p*2, p*2+1

    #pragma unroll
    for (int kc = 0; kc < 8; ++kc) {
        f16x8 bfr[4];
        #pragma unroll
        for (int ni = 0; ni < 4; ++ni)
            bfr[ni] = *(const f16x8*)(bbase + (size_t)(ni * 8 + kc) * 512);
        f16x8 vbA = *(const f16x8*)(vbase + (kc * 32 + lg * 8) * 2);
        f16x8 vbB = *(const f16x8*)(vbase + (256 + kc * 32 + lg * 8) * 2);
        const int kco = (kc * 64) ^ xm6;
        f16x8 af[8];
        f16x8 z = {};
        #pragma unroll
        for (int mi = 0; mi < 8; ++mi) {
            f16x8 uv = *(const f16x8*)(ubase + uoff[mi] + kco);
            af[mi] = __builtin_elementwise_max(uv + (mi < 4 ? vbA : vbB), z);
        }
        __builtin_amdgcn_s_setprio(1);
        #pragma unroll
        for (int mi = 0; mi < 8; ++mi)
            #pragma unroll
            for (int ni = 0; ni < 4; ++ni)
                acc[mi][ni] = __builtin_amdgcn_mfma_f32_16x16x32_f16(
                    af[mi], bfr[ni], acc[mi][ni], 0, 0, 0);
        __builtin_amdgcn_s_setprio(0);
    }

    // ---- epilogue: relu * edge_w, reduce, accumulate into smAgg ----
    float rsum[2][4];
    #pragma unroll
    for (int rl = 0; rl < 2; ++rl)
        #pragma unroll
        for (int ni = 0; ni < 4; ++ni) rsum[rl][ni] = 0.0f;

    #pragma unroll
    for (int mi = 0; mi < 8; ++mi) {
        int rl = mi >> 2;
        #pragma unroll
        for (int rr = 0; rr < 4; ++rr) {
            // C/D: col = lane&15, row = (lane>>4)*4 + rr  [m89/m91]; sender s = (mi&3)*16 + row
            float w = smWgt[k * 512 + (p * 2 + rl) * 64 + (mi & 3) * 16 + lg * 4 + rr];
            #pragma unroll
            for (int ni = 0; ni < 4; ++ni)
                rsum[rl][ni] += fmaxf(acc[mi][ni][rr], 0.0f) * w;
        }
    }
    #pragma unroll
    for (int rl = 0; rl < 2; ++rl)
        #pragma unroll
        for (int ni = 0; ni < 4; ++ni) {
            rsum[rl][ni] += __shfl_xor(rsum[rl][ni], 16, 64);
            rsum[rl][ni] += __shfl_xor(rsum[rl][ni], 32, 64);
        }
    if (lane < 16) {
        #pragma unroll
        for (int rl = 0; rl < 2; ++rl)
            #pragma unroll
            for (int ni = 0; ni < 4; ++ni) {
                int idx = (p * 2 + rl) * 256 + q * 64 + ni * 16 + ln15;
                float v = rsum[rl][ni];
                if (k) v += smAgg[idx];
                smAgg[idx] = v;
            }
    }
}

// Fused per-stage kernel: edge-GEMM + aggregation + node MLP + RK4 tail.
// Block = (batch, 8 receivers), 512 threads, grid 256 = 1 block/CU (2 waves/SIMD:
// 128 VGPR + 128 AGPR). agg stays in LDS. v6: phase-D MLP weights (Wo1/Wo2) are
// streamed through LDS in 32-row double-buffered chunks via global_load_lds
// (DMA overlaps compute; kills the 500-scalar-load latency chain of v5).
__global__ __launch_bounds__(512, 2)
void stage_kernel(int stage, int step,
    const float* __restrict__ edges, const float* __restrict__ W1g,
    const float* __restrict__ b1g,   const _Float16* __restrict__ W2F,
    const float* __restrict__ b2g,
    const float* __restrict__ Wo1, const float* __restrict__ bo1,
    const float* __restrict__ Wo2, const float* __restrict__ bo2,
    const float* __restrict__ Wo3, const float* __restrict__ bo3,
    const float* __restrict__ ts,  const void* __restrict__ scp,
    const float* __restrict__ xcur, const float* __restrict__ kprev,
    float* __restrict__ kout,
    const float* __restrict__ k1b, const float* __restrict__ k2b,
    const float* __restrict__ k3b,
    float* __restrict__ xnext, float* __restrict__ outp)
{
    extern __shared__ char smem[];
    _Float16* smVBH = (_Float16*)(smem + OFF_VB);
    float*  smY   = (float*)(smem + OFF_Y);
    float*  smWgt = (float*)(smem + OFF_WGT);
    float*  smAgg = (float*)(smem + OFF_AGG);

    const int tid = threadIdx.x;
    const int b   = blockIdx.x >> 3;
    const int rg  = blockIdx.x & 7;
    const int r0  = rg * 8;

    const float dt = load_dt(ts, scp, step);
    const float cc = (stage == 0) ? 0.0f : ((stage == 3) ? 1.0f : 0.5f);

    // ---- P0: y (all 64 nodes), edge weights (sender-major) ----
    if (tid < 256) {
        int gi = (b * NN) * FF + tid;           // tid = n*4+f
        float y = xcur[gi];
        if (stage != 0) y += cc * dt * kprev[gi];
        smY[tid] = scrub(y);
    }
    #pragma unroll
    for (int it = 0; it < 2; ++it) {
        // smWgt[k][rv][s] ; diagonal s==r -> 0
        int i = tid + it * 512;
        int k = i >> 9, m = i & 511;
        int rv = m >> 6, s = m & 63;
        int r = r0 + rv;
        float w = 0.0f;
        if (s != r) {
            int j = s - (s > r ? 1 : 0);
            w = edges[((size_t)b * EE + r * 63 + j) * KK + k];
        }
        smWgt[i] = w;
    }

    const int lane = tid & 63;
    const int wn   = tid >> 6;    // 8 waves: p = wn>>1 (receiver pair 0..3), ch = wn&1 (col half)
    const int p    = wn >> 1;
    const int ch   = wn & 1;
    const int ln15 = lane & 15;
    const int lg   = lane >> 4;   // 0..3

    // swizzled u read offsets: byte = s*512 + ((kc*64 + lg*16) ^ ((s&7)<<4)),
    // s = (mi&3)*16 + ln15 -> s&7 = ln15&7 (per-lane constant).
    const int xm45 = (ln15 & 3) << 4;
    const int xm6  = (ln15 & 4) << 4;
    int uoff[8];
    #pragma unroll
    for (int mi = 0; mi < 8; ++mi) {
        int s = (mi & 3) * 16 + ln15;
        uoff[mi] = s * 512 + ((lg * 16) ^ xm45);
    }

    __syncthreads();              // smY/smWgt ready

    // ---- build k=0 into buf0 ----
    build_uk(smem, 0, 0, tid, W1g, smY);
    build_vbh(smVBH, 0, 0, tid, r0, W1g, b1g, smY);
    __syncthreads();              // u0/vbh0 ready

    // ---- build k=1 (VALU) interleaves with GEMM k=0 (MFMA) ----
    build_uk(smem, 1, 1, tid, W1g, smY);
    build_vbh(smVBH, 1, 1, tid, r0, W1g, b1g, smY);
    gemm_pass(smem, 0, 0, ch * 2 + 0, p, W2F, b2g, smWgt, smAgg, lane, ln15, lg, uoff, xm6);
    gemm_pass(smem, 0, 0, ch * 2 + 1, p, W2F, b2g, smWgt, smAgg, lane, ln15, lg, uoff, xm6);
    __syncthreads();              // u1/vbh1 ready
    gemm_pass(smem, 1, 1, ch * 2 + 0, p, W2F, b2g, smWgt, smAgg, lane, ln15, lg, uoff, xm6);
    gemm_pass(smem, 1, 1, ch * 2 + 1, p, W2F, b2g, smWgt, smAgg, lane, ln15, lg, uoff, xm6);
    __syncthreads();              // smAgg complete; u region free for reuse

    // ======== phase D: node MLP for the block's 8 nodes (rows r0..r0+7) ========
    float* ldsW  = (float*)(smem + OFF_U0);    // [2][32][256] f32 chunk dbuf
    float* smAug = (float*)(smem + OFF_AUG);   // [8][264]
    float* smP1  = (float*)(smem + OFF_P1);    // [8][256]
    float* smP2  = (float*)(smem + OFF_P2);    // [8][256]

    // issue Wo1 chunk 0 DMA early (overlaps aug build)
    stage32rows(Wo1, (char*)ldsW, tid);

    // ---- aug = [y(4) | agg(256)] per row ----
    for (int u = tid; u < 2080; u += 512) {
        int rr = u / 260, h = u - rr * 260;
        float v;
        if (h < 4) v = smY[(r0 + rr) * 4 + h];
        else       v = smAgg[rr * 256 + (h - 4)];
        smAug[rr * 264 + h] = v;
    }
    __syncthreads();   // aug ready + Wo1 chunk0 drained

    const int rh = tid >> 8;      // row half: rows rh*4 .. rh*4+3
    const int c  = tid & 255;

    // ---- L1: 260 -> 256, relu (Wo1 streamed via LDS chunks) ----
    {
        float a[4];
        float b0 = bo1[c];
        float wt[4];               // tail rows 256..259: hoist loads
        #pragma unroll
        for (int j = 0; j < 4; ++j) wt[j] = Wo1[(size_t)(256 + j) * 256 + c];
        #pragma unroll
        for (int rr = 0; rr < 4; ++rr) a[rr] = b0;
        #pragma unroll 1
        for (int ck = 0; ck < 8; ++ck) {
            if (ck < 7)
                stage32rows(Wo1 + (size_t)(ck + 1) * 32 * 256,
                            (char*)ldsW + ((ck + 1) & 1) * 32768, tid);
            const float* wb = ldsW + (ck & 1) * 8192;
            #pragma unroll
            for (int hb2 = 0; hb2 < 4; ++hb2) {
                int hb = ck * 32 + hb2 * 8;
                float w[8];
                #pragma unroll
                for (int j = 0; j < 8; ++j) w[j] = wb[(hb2 * 8 + j) * 256 + c];
                f32x4v xlo[4], xhi[4];
                #pragma unroll
                for (int rr = 0; rr < 4; ++rr) {
                    xlo[rr] = *(const f32x4v*)(smAug + (rh * 4 + rr) * 264 + hb);
                    xhi[rr] = *(const f32x4v*)(smAug + (rh * 4 + rr) * 264 + hb + 4);
                }
                #pragma unroll
                for (int jj = 0; jj < 4; ++jj)
                    #pragma unroll
                    for (int rr = 0; rr < 4; ++rr) {
                        a[rr] += xlo[rr][jj] * w[jj];
                        a[rr] += xhi[rr][jj] * w[4 + jj];
                    }
            }
            __syncthreads();       // chunk ck+1 DMA drained; buf (ck&1) readers done
        }
        // issue Wo2 chunk 0 DMA (overlaps tail + P1 write)
        stage32rows(Wo2, (char*)ldsW, tid);
        #pragma unroll
        for (int j = 0; j < 4; ++j) {          // tail h = 256..259
            #pragma unroll
            for (int rr = 0; rr < 4; ++rr)
                a[rr] += smAug[(rh * 4 + rr) * 264 + 256 + j] * wt[j];
        }
        #pragma unroll
        for (int rr = 0; rr < 4; ++rr)
            smP1[(rh * 4 + rr) * 256 + c] = fmaxf(a[rr], 0.0f);
    }
    __syncthreads();   // P1 ready + Wo2 chunk0 drained
    // ---- L2: 256 -> 256, relu (Wo2 streamed via LDS chunks) ----
    {
        float a[4];
        float b0 = bo2[c];
        #pragma unroll
        for (int rr = 0; rr < 4; ++rr) a[rr] = b0;
        #pragma unroll 1
        for (int ck = 0; ck < 8; ++ck) {
            if (ck < 7)
                stage32rows(Wo2 + (size_t)(ck + 1) * 32 * 256,
                            (char*)ldsW + ((ck + 1) & 1) * 32768, tid);
            const float* wb = ldsW + (ck & 1) * 8192;
            #pragma unroll
            for (int hb2 = 0; hb2 < 4; ++hb2) {
                int hb = ck * 32 + hb2 * 8;
                float w[8];
                #pragma unroll
                for (int j = 0; j < 8; ++j) w[j] = wb[(hb2 * 8 + j) * 256 + c];
                f32x4v xlo[4], xhi[4];
                #pragma unroll
                for (int rr = 0; rr < 4; ++rr) {
                    xlo[rr] = *(const f32x4v*)(smP1 + (rh * 4 + rr) * 256 + hb);
                    xhi[rr] = *(const f32x4v*)(smP1 + (rh * 4 + rr) * 256 + hb + 4);
                }
                #pragma unroll
                for (int jj = 0; jj < 4; ++jj)
                    #pragma unroll
                    for (int rr = 0; rr < 4; ++rr) {
                        a[rr] += xlo[rr][jj] * w[jj];
                        a[rr] += xhi[rr][jj] * w[4 + jj];
                    }
            }
            __syncthreads();
        }
        #pragma unroll
        for (int rr = 0; rr < 4; ++rr)
            smP2[(rh * 4 + rr) * 256 + c] = fmaxf(a[rr], 0.0f);
    }
    __syncthreads();
    // ---- L3 (256 -> 4) + residual + RK4 tail ----
    {
        int rr = tid >> 6, f = (tid >> 4) & 3, hs = tid & 15;   // one wave per row, 8 rows
        float part = 0.0f;
        #pragma unroll
        for (int j = 0; j < 16; ++j) {
            int h = hs + j * 16;
            part += smP2[rr * 256 + h] * Wo3[h * 4 + f];
        }
        part += __shfl_xor(part, 8, 64);
        part += __shfl_xor(part, 4, 64);
        part += __shfl_xor(part, 2, 64);
        part += __shfl_xor(part, 1, 64);
        if (hs == 0) {
            int grow = b * NN + r0 + rr;
            int gi   = grow * 4 + f;
            float y = smY[(r0 + rr) * 4 + f];
            float knew = scrub(y + bo3[f] + part);    // f(y) = y + p
            if (stage < 3) {
                kout[gi] = knew;
            } else {
                float xn = scrub(xcur[gi] + (dt * (1.0f / 6.0f)) *
                           (k1b[gi] + 2.0f * k2b[gi] + 2.0f * k3b[gi] + knew));
                xnext[gi] = xn;
                // out layout (B, N, NSTEP, F): row = b*64+n
                outp[(size_t)grow * NSTEP * FF + step * FF + f] = xn;
            }
        }
    }
}

// Pre-swizzle W2 -> fragment-major W2F (verified): chunk (k,ot,kc) is
// 1 KiB; lane l holds B[o = ot*16 + (l&15)][h = kc*32 + (l>>4)*8 + e]
__global__ void swizzle_w2(const float* __restrict__ W2, _Float16* __restrict__ W2F)
{
    int idx = blockIdx.x * 256 + threadIdx.x;       // 0 .. 131071
    int k   = idx >> 16;
    int rem = idx & 65535;
    int ch  = rem >> 9;
    int pos = rem & 511;
    int ot  = ch >> 3, kc = ch & 7;
    int l   = pos >> 3, e = pos & 7;
    int o   = ot * 16 + (l & 15);
    int h   = kc * 32 + (l >> 4) * 8 + e;
    W2F[idx] = (_Float16)W2[(size_t)(k * 256 + h) * 256 + o];
}

__global__ void init_x(const float* __restrict__ inp, float* __restrict__ x0)
{
    int i = blockIdx.x * 256 + threadIdx.x;   // i = (b*64+n)*4+f
    if (i < BB * NN * FF) {
        int f = i & 3, bn = i >> 2;
        x0[i] = scrub(inp[(size_t)(bn * TT) * FF + f]);   // inputs[b][n][0][f]
    }
}

static int find_input(const int* in_sizes, int n_in, int want, unsigned char* used, int dflt) {
    if (dflt >= 0 && dflt < n_in && in_sizes[dflt] == want && !used[dflt]) { used[dflt] = 1; return dflt; }
    for (int i = 0; i < n_in; ++i)
        if (!used[i] && in_sizes[i] == want) { used[i] = 1; return i; }
    return dflt;
}

extern "C" void kernel_launch(void* const* d_in, const int* in_sizes, int n_in,
                              void* d_out, int out_size, void* d_ws, size_t ws_size,
                              hipStream_t stream)
{
    unsigned char used[64] = {0};
    int iInp = find_input(in_sizes, n_in, BB*NN*TT*FF, used, 0);
    int iEdg = find_input(in_sizes, n_in, BB*EE*KK,    used, 1);
    (void)find_input(in_sizes, n_in, EE*NN, used, 2);              // rel_rec (unused)
    (void)find_input(in_sizes, n_in, EE*NN, used, 3);              // rel_send (unused)
    int iW1  = find_input(in_sizes, n_in, KK*8*256,  used, 4);
    int ib1  = find_input(in_sizes, n_in, KK*256,    used, 5);
    int iW2  = find_input(in_sizes, n_in, KK*256*256,used, 6);
    int ib2  = find_input(in_sizes, n_in, KK*256,    used, 7);
    int iWo1 = find_input(in_sizes, n_in, 260*256,   used, 8);
    int ibo1 = find_input(in_sizes, n_in, 256,       used, 9);
    int iWo2 = find_input(in_sizes, n_in, 256*256,   used, 10);
    int ibo2 = find_input(in_sizes, n_in, 256,       used, 11);
    int iWo3 = find_input(in_sizes, n_in, 256*4,     used, 12);
    int ibo3 = find_input(in_sizes, n_in, 4,         used, 13);
    int iTs  = find_input(in_sizes, n_in, TT,        used, 14);
    (void)find_input(in_sizes, n_in, 1, used, 15);                 // pred_steps
    int iSc  = find_input(in_sizes, n_in, 1,         used, 16);    // scale

    const float* inputs = (const float*)d_in[iInp];
    const float* edges  = (const float*)d_in[iEdg];
    const float* W1  = (const float*)d_in[iW1];
    const float* b1  = (const float*)d_in[ib1];
    const float* W2  = (const float*)d_in[iW2];
    const float* b2  = (const float*)d_in[ib2];
    const float* Wo1 = (const float*)d_in[iWo1];
    const float* bo1 = (const float*)d_in[ibo1];
    const float* Wo2 = (const float*)d_in[iWo2];
    const float* bo2 = (const float*)d_in[ibo2];
    const float* Wo3 = (const float*)d_in[iWo3];
    const float* bo3 = (const float*)d_in[ibo3];
    const float* ts  = (const float*)d_in[iTs];
    const void*  scp = d_in[iSc];

    char* ws = (char*)d_ws;
    _Float16* W2F = (_Float16*)ws;                     // 262144 B
    float* xA  = (float*)(ws + 262144);
    float* xB  = (float*)(ws + 262144 + 1 * 32768);
    float* k1  = (float*)(ws + 262144 + 2 * 32768);
    float* k2  = (float*)(ws + 262144 + 3 * 32768);
    float* k3  = (float*)(ws + 262144 + 4 * 32768);

    float* outp = (float*)d_out;   // f32 output

    (void)hipFuncSetAttribute((const void*)stage_kernel,
        hipFuncAttributeMaxDynamicSharedMemorySize, SMEM2);

    swizzle_w2<<<dim3(512), dim3(256), 0, stream>>>(W2, W2F);
    init_x<<<dim3(32), dim3(256), 0, stream>>>(inputs, xA);

    float* xc = xA;
    float* xn = xB;
    for (int step = 0; step < NSTEP; ++step) {
        float* kprevs[4] = { xc, k1, k2, k3 };   // kprev per stage (xc unused at s0)
        float* kouts[4]  = { k1, k2, k3, k3 };   // kout per stage (s3 -> tail path)
        for (int s = 0; s < 4; ++s) {
            stage_kernel<<<dim3(256), dim3(512), SMEM2, stream>>>(s, step,
                edges, W1, b1, W2F, b2,
                Wo1, bo1, Wo2, bo2, Wo3, bo3, ts, scp, xc, kprevs[s],
                kouts[s], k1, k2, k3, xn, outp);
        }
        float* t = xc; xc = xn; xn = t;
    }
}

// Round 7
// 2197.883 us; speedup vs baseline: 1.0122x; 1.0122x over previous
//
#include <hip/hip_runtime.h>

// Problem constants (fixed by setup_inputs)
#define BB 32
#define NN 64
#define TT 11
#define FF 4
#define KK 2
#define EE 4032      // N*(N-1)
#define NSTEP 10

typedef _Float16 f16x8 __attribute__((ext_vector_type(8)));
typedef float    f32x4v __attribute__((ext_vector_type(4)));

// ---- fused kernel LDS (per block; 2 blocks/CU -> 2x75K = 150K <= 160K) ----
// phase C: u dbuf [2][64][512B XOR-swz] 64K | vbh dbuf [2][4][256]f16 4K |
//          y [64][4]f32 1K | wgt [2][4][64]f32 2K | agg [4][256]f32 4K
// phase D aliases the u region: aug[4][264]f32 | P1[4][256] | P2[4][256]
#define OFF_U0   0
#define OFF_VB   65536
#define OFF_Y    69632
#define OFF_WGT  70656
#define OFF_AGG  72704
#define SMEM2    76800
#define OFF_AUG  0
#define OFF_P1   8448
#define OFF_P2   16640

__device__ __forceinline__ float scrub(float v) {
    return fminf(fmaxf(v, -3.0e4f), 3.0e4f);   // inactive when correct (|x| <~ 600)
}

__device__ __forceinline__ float load_dt(const float* ts, const void* scp, int step) {
    float t0 = ts[step], t1 = ts[step + 1];
    int w = ((const int*)scp)[0];
    float scl;
    if (w > 0 && w < 1000000) scl = (float)w;            // int32 (live path)
    else {
        float f = __int_as_float(w);
        scl = (f > 0.5f && f < 1.0e6f) ? f : 10.0f;
    }
    return (t1 - t0) / scl;
}

// u-build (256 thr): u[s][h] = sum_f y_s[f] * W1send[k][f][h], f16, XOR-swizzled rows.
__device__ __forceinline__ void build_uk(char* smem, int buf, int k, int tid,
    const float* __restrict__ W1g, const float* smY)
{
    int hg = tid & 31, sb = tid >> 5;          // sb = 0..7
    const float* w1p = W1g + k * 2048 + hg * 8;
    f32x4v wA[4], wB[4];
    #pragma unroll
    for (int f = 0; f < 4; ++f) {
        wA[f] = *(const f32x4v*)(w1p + f * 256);
        wB[f] = *(const f32x4v*)(w1p + f * 256 + 4);
    }
    const int swz = (hg * 16) ^ (sb << 4);     // s&7 == sb (it*8 ≡ 0 mod 8)
    char* ub = smem + OFF_U0 + buf * 32768;
    #pragma unroll
    for (int it = 0; it < 8; ++it) {
        int s = sb + it * 8;
        f32x4v yv = *(const f32x4v*)(smY + s * 4);
        f16x8 uv;
        #pragma unroll
        for (int e = 0; e < 4; ++e) {
            float vA = yv[0]*wA[0][e] + yv[1]*wA[1][e] + yv[2]*wA[2][e] + yv[3]*wA[3][e];
            float vB = yv[0]*wB[0][e] + yv[1]*wB[1][e] + yv[2]*wB[2][e] + yv[3]*wB[3][e];
            uv[e]     = (_Float16)vA;
            uv[e + 4] = (_Float16)vB;
        }
        *(f16x8*)(ub + s * 512 + swz) = uv;
    }
}

// vbh[buf][rv][h] = f16( b1 + sum_f y_recv[f] * W1recv[k][f][h] ), rv = 0..3
__device__ __forceinline__ void build_vbh(_Float16* smVBH, int buf, int k, int tid, int r0,
    const float* __restrict__ W1g, const float* __restrict__ b1g, const float* smY)
{
    #pragma unroll
    for (int it = 0; it < 4; ++it) {
        int i = tid + it * 256;
        int rv = i >> 8, h = i & 255;
        float acch = b1g[k * 256 + h];
        #pragma unroll
        for (int f = 0; f < 4; ++f)
            acch += smY[(r0 + rv) * 4 + f] * W1g[k * 2048 + (4 + f) * 256 + h];
        smVBH[buf * 1024 + i] = (_Float16)acch;
    }
}

// One GEMM pass: 128 rows (pair p: 2 receivers x 64 senders) x 64 cols (quarter q),
// one k. Accumulates relu(acc)*w into smAgg (k==0 stores, k==1 adds).
__device__ __forceinline__ void gemm_pass(char* smem, int buf, int k, int q, int p,
    const _Float16* __restrict__ W2F, const float* __restrict__ b2g,
    const float* smWgt, float* smAgg,
    int lane, int ln15, int lg, const int* uoff, int xm6)
{
    const _Float16* smVBH = (const _Float16*)(smem + OFF_VB);

    float bv[4];
    #pragma unroll
    for (int ni = 0; ni < 4; ++ni)
        bv[ni] = b2g[k * 256 + q * 64 + ni * 16 + ln15];

    f32x4v acc[8][4];         // b2 folded into init
    #pragma unroll
    for (int mi = 0; mi < 8; ++mi)
        #pragma unroll
        for (int ni = 0; ni < 4; ++ni)
            acc[mi][ni] = (f32x4v){bv[ni], bv[ni], bv[ni], bv[ni]};

    const _Float16* bbase = W2F + ((size_t)((k * 16 + q * 4) * 8)) * 512 + lane * 8;
    const char* ubase = smem + OFF_U0 + buf * 32768;
    const char* vbase = (const char*)(smVBH + buf * 1024 + p * 512);  // rows p*2, p*2+1

    #pragma unroll
    for (int kc = 0; kc < 8; ++kc) {
        f16x8 bfr[4];
        #pragma unroll
        for (int ni = 0; ni < 4; ++ni)
            bfr[ni] = *(const f16x8*)(bbase + (size_t)(ni * 8 + kc) * 512);
        f16x8 vbA = *(const f16x8*)(vbase + (kc * 32 + lg * 8) * 2);
        f16x8 vbB = *(const f16x8*)(vbase + (256 + kc * 32 + lg * 8) * 2);
        const int kco = (kc * 64) ^ xm6;
        f16x8 af[8];
        f16x8 z = {};
        #pragma unroll
        for (int mi = 0; mi < 8; ++mi) {
            f16x8 uv = *(const f16x8*)(ubase + uoff[mi] + kco);
            af[mi] = __builtin_elementwise_max(uv + (mi < 4 ? vbA : vbB), z);
        }
        __builtin_amdgcn_s_setprio(1);
        #pragma unroll
        for (int mi = 0; mi < 8; ++mi)
            #pragma unroll
            for (int ni = 0; ni < 4; ++ni)
                acc[mi][ni] = __builtin_amdgcn_mfma_f32_16x16x32_f16(
                    af[mi], bfr[ni], acc[mi][ni], 0, 0, 0);
        __builtin_amdgcn_s_setprio(0);
    }

    // ---- epilogue: relu * edge_w, reduce, accumulate into smAgg ----
    float rsum[2][4];
    #pragma unroll
    for (int rl = 0; rl < 2; ++rl)
        #pragma unroll
        for (int ni = 0; ni < 4; ++ni) rsum[rl][ni] = 0.0f;

    #pragma unroll
    for (int mi = 0; mi < 8; ++mi) {
        int rl = mi >> 2;
        #pragma unroll
        for (int rr = 0; rr < 4; ++rr) {
            // C/D: col = lane&15, row = (lane>>4)*4 + rr  [m89/m91]; sender s = (mi&3)*16 + row
            float w = smWgt[k * 256 + (p * 2 + rl) * 64 + (mi & 3) * 16 + lg * 4 + rr];
            #pragma unroll
            for (int ni = 0; ni < 4; ++ni)
                rsum[rl][ni] += fmaxf(acc[mi][ni][rr], 0.0f) * w;
        }
    }
    #pragma unroll
    for (int rl = 0; rl < 2; ++rl)
        #pragma unroll
        for (int ni = 0; ni < 4; ++ni) {
            rsum[rl][ni] += __shfl_xor(rsum[rl][ni], 16, 64);
            rsum[rl][ni] += __shfl_xor(rsum[rl][ni], 32, 64);
        }
    if (lane < 16) {
        #pragma unroll
        for (int rl = 0; rl < 2; ++rl)
            #pragma unroll
            for (int ni = 0; ni < 4; ++ni) {
                int idx = (p * 2 + rl) * 256 + q * 64 + ni * 16 + ln15;
                float v = rsum[rl][ni];
                if (k) v += smAgg[idx];
                smAgg[idx] = v;
            }
    }
}

// Fused per-stage kernel: edge-GEMM + aggregation + node MLP + RK4 tail.
// v7: block = (batch, 4 receivers), 256 threads / 4 waves, grid 512 -> TWO independent
// blocks per CU (8 waves/CU at 256 regs, LDS 75K x 2 = 150K). Cross-block phase
// overlap: while one block stalls in the latency-bound MLP or barrier drains, the
// co-resident block's GEMM waves feed the MFMA pipe (m114: time ~ max, not sum).
// GEMM inner loop, k-pipelined dbuf build, and scalar MLP tail proven in v5.
__global__ __launch_bounds__(256, 2)
void stage_kernel(int stage, int step,
    const float* __restrict__ edges, const float* __restrict__ W1g,
    const float* __restrict__ b1g,   const _Float16* __restrict__ W2F,
    const float* __restrict__ b2g,
    const float* __restrict__ Wo1, const float* __restrict__ bo1,
    const float* __restrict__ Wo2, const float* __restrict__ bo2,
    const float* __restrict__ Wo3, const float* __restrict__ bo3,
    const float* __restrict__ ts,  const void* __restrict__ scp,
    const float* __restrict__ xcur, const float* __restrict__ kprev,
    float* __restrict__ kout,
    const float* __restrict__ k1b, const float* __restrict__ k2b,
    const float* __restrict__ k3b,
    float* __restrict__ xnext, float* __restrict__ outp)
{
    extern __shared__ char smem[];
    _Float16* smVBH = (_Float16*)(smem + OFF_VB);
    float*  smY   = (float*)(smem + OFF_Y);
    float*  smWgt = (float*)(smem + OFF_WGT);
    float*  smAgg = (float*)(smem + OFF_AGG);

    const int tid = threadIdx.x;
    const int b   = blockIdx.x >> 4;
    const int rg  = blockIdx.x & 15;
    const int r0  = rg * 4;

    const float dt = load_dt(ts, scp, step);
    const float cc = (stage == 0) ? 0.0f : ((stage == 3) ? 1.0f : 0.5f);

    // ---- P0: y (all 64 nodes), edge weights (sender-major) ----
    {
        int gi = (b * NN) * FF + tid;           // tid = n*4+f
        float y = xcur[gi];
        if (stage != 0) y += cc * dt * kprev[gi];
        smY[tid] = scrub(y);
    }
    #pragma unroll
    for (int it = 0; it < 2; ++it) {
        // smWgt[k][rv][s] ; diagonal s==r -> 0
        int i = tid + it * 256;
        int k = i >> 8, m = i & 255;
        int rv = m >> 6, s = m & 63;
        int r = r0 + rv;
        float w = 0.0f;
        if (s != r) {
            int j = s - (s > r ? 1 : 0);
            w = edges[((size_t)b * EE + r * 63 + j) * KK + k];
        }
        smWgt[i] = w;
    }

    const int lane = tid & 63;
    const int wn   = tid >> 6;    // 4 waves: p = wn>>1 (receiver pair 0/1), ch = wn&1 (col half)
    const int p    = wn >> 1;
    const int ch   = wn & 1;
    const int ln15 = lane & 15;
    const int lg   = lane >> 4;   // 0..3

    // swizzled u read offsets: byte = s*512 + ((kc*64 + lg*16) ^ ((s&7)<<4)),
    // s = (mi&3)*16 + ln15 -> s&7 = ln15&7 (per-lane constant).
    const int xm45 = (ln15 & 3) << 4;
    const int xm6  = (ln15 & 4) << 4;
    int uoff[8];
    #pragma unroll
    for (int mi = 0; mi < 8; ++mi) {
        int s = (mi & 3) * 16 + ln15;
        uoff[mi] = s * 512 + ((lg * 16) ^ xm45);
    }

    __syncthreads();              // smY/smWgt ready

    // ---- build k=0 into buf0 ----
    build_uk(smem, 0, 0, tid, W1g, smY);
    build_vbh(smVBH, 0, 0, tid, r0, W1g, b1g, smY);
    __syncthreads();              // u0/vbh0 ready

    // ---- build k=1 (VALU) interleaves with GEMM k=0 (MFMA) ----
    build_uk(smem, 1, 1, tid, W1g, smY);
    build_vbh(smVBH, 1, 1, tid, r0, W1g, b1g, smY);
    gemm_pass(smem, 0, 0, ch * 2 + 0, p, W2F, b2g, smWgt, smAgg, lane, ln15, lg, uoff, xm6);
    gemm_pass(smem, 0, 0, ch * 2 + 1, p, W2F, b2g, smWgt, smAgg, lane, ln15, lg, uoff, xm6);
    __syncthreads();              // u1/vbh1 ready
    gemm_pass(smem, 1, 1, ch * 2 + 0, p, W2F, b2g, smWgt, smAgg, lane, ln15, lg, uoff, xm6);
    gemm_pass(smem, 1, 1, ch * 2 + 1, p, W2F, b2g, smWgt, smAgg, lane, ln15, lg, uoff, xm6);
    __syncthreads();              // smAgg complete; u region free for aliasing

    // ======== phase D: node MLP for the block's 4 nodes (rows r0..r0+3) ========
    float* smAug = (float*)(smem + OFF_AUG);   // [4][264]
    float* smP1  = (float*)(smem + OFF_P1);    // [4][256]
    float* smP2  = (float*)(smem + OFF_P2);    // [4][256]

    // ---- aug = [y(4) | agg(256)] per row ----
    for (int u = tid; u < 1040; u += 256) {
        int rr = u / 260, h = u - rr * 260;
        float v;
        if (h < 4) v = smY[(r0 + rr) * 4 + h];
        else       v = smAgg[rr * 256 + (h - 4)];
        smAug[rr * 264 + h] = v;
    }
    __syncthreads();

    const int c = tid;

    // ---- L1: 260 -> 256, relu ----
    {
        float a[4];
        float b0 = bo1[c];
        #pragma unroll
        for (int rr = 0; rr < 4; ++rr) a[rr] = b0;
        #pragma unroll 1
        for (int hb = 0; hb < 256; hb += 8) {
            float w[8];
            #pragma unroll
            for (int j = 0; j < 8; ++j) w[j] = Wo1[(size_t)(hb + j) * 256 + c];
            f32x4v xlo[4], xhi[4];
            #pragma unroll
            for (int rr = 0; rr < 4; ++rr) {
                xlo[rr] = *(const f32x4v*)(smAug + rr * 264 + hb);
                xhi[rr] = *(const f32x4v*)(smAug + rr * 264 + hb + 4);
            }
            #pragma unroll
            for (int jj = 0; jj < 4; ++jj)
                #pragma unroll
                for (int rr = 0; rr < 4; ++rr) {
                    a[rr] += xlo[rr][jj] * w[jj];
                    a[rr] += xhi[rr][jj] * w[4 + jj];
                }
        }
        #pragma unroll
        for (int j = 0; j < 4; ++j) {          // tail h = 256..259
            float wv = Wo1[(size_t)(256 + j) * 256 + c];
            #pragma unroll
            for (int rr = 0; rr < 4; ++rr)
                a[rr] += smAug[rr * 264 + 256 + j] * wv;
        }
        #pragma unroll
        for (int rr = 0; rr < 4; ++rr)
            smP1[rr * 256 + c] = fmaxf(a[rr], 0.0f);
    }
    __syncthreads();
    // ---- L2: 256 -> 256, relu ----
    {
        float a[4];
        float b0 = bo2[c];
        #pragma unroll
        for (int rr = 0; rr < 4; ++rr) a[rr] = b0;
        #pragma unroll 1
        for (int hb = 0; hb < 256; hb += 8) {
            float w[8];
            #pragma unroll
            for (int j = 0; j < 8; ++j) w[j] = Wo2[(size_t)(hb + j) * 256 + c];
            f32x4v xlo[4], xhi[4];
            #pragma unroll
            for (int rr = 0; rr < 4; ++rr) {
                xlo[rr] = *(const f32x4v*)(smP1 + rr * 256 + hb);
                xhi[rr] = *(const f32x4v*)(smP1 + rr * 256 + hb + 4);
            }
            #pragma unroll
            for (int jj = 0; jj < 4; ++jj)
                #pragma unroll
                for (int rr = 0; rr < 4; ++rr) {
                    a[rr] += xlo[rr][jj] * w[jj];
                    a[rr] += xhi[rr][jj] * w[4 + jj];
                }
        }
        #pragma unroll
        for (int rr = 0; rr < 4; ++rr)
            smP2[rr * 256 + c] = fmaxf(a[rr], 0.0f);
    }
    __syncthreads();
    // ---- L3 (256 -> 4) + residual + RK4 tail ----
    {
        int rr = tid >> 6, f = (tid >> 4) & 3, hs = tid & 15;   // one wave per row, 4 rows
        float part = 0.0f;
        #pragma unroll
        for (int j = 0; j < 16; ++j) {
            int h = hs + j * 16;
            part += smP2[rr * 256 + h] * Wo3[h * 4 + f];
        }
        part += __shfl_xor(part, 8, 64);
        part += __shfl_xor(part, 4, 64);
        part += __shfl_xor(part, 2, 64);
        part += __shfl_xor(part, 1, 64);
        if (hs == 0) {
            int grow = b * NN + r0 + rr;
            int gi   = grow * 4 + f;
            float y = smY[(r0 + rr) * 4 + f];
            float knew = scrub(y + bo3[f] + part);    // f(y) = y + p
            if (stage < 3) {
                kout[gi] = knew;
            } else {
                float xn = scrub(xcur[gi] + (dt * (1.0f / 6.0f)) *
                           (k1b[gi] + 2.0f * k2b[gi] + 2.0f * k3b[gi] + knew));
                xnext[gi] = xn;
                // out layout (B, N, NSTEP, F): row = b*64+n
                outp[(size_t)grow * NSTEP * FF + step * FF + f] = xn;
            }
        }
    }
}

// Pre-swizzle W2 -> fragment-major W2F (verified): chunk (k,ot,kc) is
// 1 KiB; lane l holds B[o = ot*16 + (l&15)][h = kc*32 + (l>>4)*8 + e]
__global__ void swizzle_w2(const float* __restrict__ W2, _Float16* __restrict__ W2F)
{
    int idx = blockIdx.x * 256 + threadIdx.x;       // 0 .. 131071
    int k   = idx >> 16;
    int rem = idx & 65535;
    int ch  = rem >> 9;
    int pos = rem & 511;
    int ot  = ch >> 3, kc = ch & 7;
    int l   = pos >> 3, e = pos & 7;
    int o   = ot * 16 + (l & 15);
    int h   = kc * 32 + (l >> 4) * 8 + e;
    W2F[idx] = (_Float16)W2[(size_t)(k * 256 + h) * 256 + o];
}

__global__ void init_x(const float* __restrict__ inp, float* __restrict__ x0)
{
    int i = blockIdx.x * 256 + threadIdx.x;   // i = (b*64+n)*4+f
    if (i < BB * NN * FF) {
        int f = i & 3, bn = i >> 2;
        x0[i] = scrub(inp[(size_t)(bn * TT) * FF + f]);   // inputs[b][n][0][f]
    }
}

static int find_input(const int* in_sizes, int n_in, int want, unsigned char* used, int dflt) {
    if (dflt >= 0 && dflt < n_in && in_sizes[dflt] == want && !used[dflt]) { used[dflt] = 1; return dflt; }
    for (int i = 0; i < n_in; ++i)
        if (!used[i] && in_sizes[i] == want) { used[i] = 1; return i; }
    return dflt;
}

extern "C" void kernel_launch(void* const* d_in, const int* in_sizes, int n_in,
                              void* d_out, int out_size, void* d_ws, size_t ws_size,
                              hipStream_t stream)
{
    unsigned char used[64] = {0};
    int iInp = find_input(in_sizes, n_in, BB*NN*TT*FF, used, 0);
    int iEdg = find_input(in_sizes, n_in, BB*EE*KK,    used, 1);
    (void)find_input(in_sizes, n_in, EE*NN, used, 2);              // rel_rec (unused)
    (void)find_input(in_sizes, n_in, EE*NN, used, 3);              // rel_send (unused)
    int iW1  = find_input(in_sizes, n_in, KK*8*256,  used, 4);
    int ib1  = find_input(in_sizes, n_in, KK*256,    used, 5);
    int iW2  = find_input(in_sizes, n_in, KK*256*256,used, 6);
    int ib2  = find_input(in_sizes, n_in, KK*256,    used, 7);
    int iWo1 = find_input(in_sizes, n_in, 260*256,   used, 8);
    int ibo1 = find_input(in_sizes, n_in, 256,       used, 9);
    int iWo2 = find_input(in_sizes, n_in, 256*256,   used, 10);
    int ibo2 = find_input(in_sizes, n_in, 256,       used, 11);
    int iWo3 = find_input(in_sizes, n_in, 256*4,     used, 12);
    int ibo3 = find_input(in_sizes, n_in, 4,         used, 13);
    int iTs  = find_input(in_sizes, n_in, TT,        used, 14);
    (void)find_input(in_sizes, n_in, 1, used, 15);                 // pred_steps
    int iSc  = find_input(in_sizes, n_in, 1,         used, 16);    // scale

    const float* inputs = (const float*)d_in[iInp];
    const float* edges  = (const float*)d_in[iEdg];
    const float* W1  = (const float*)d_in[iW1];
    const float* b1  = (const float*)d_in[ib1];
    const float* W2  = (const float*)d_in[iW2];
    const float* b2  = (const float*)d_in[ib2];
    const float* Wo1 = (const float*)d_in[iWo1];
    const float* bo1 = (const float*)d_in[ibo1];
    const float* Wo2 = (const float*)d_in[iWo2];
    const float* bo2 = (const float*)d_in[ibo2];
    const float* Wo3 = (const float*)d_in[iWo3];
    const float* bo3 = (const float*)d_in[ibo3];
    const float* ts  = (const float*)d_in[iTs];
    const void*  scp = d_in[iSc];

    char* ws = (char*)d_ws;
    _Float16* W2F = (_Float16*)ws;                     // 262144 B
    float* xA  = (float*)(ws + 262144);
    float* xB  = (float*)(ws + 262144 + 1 * 32768);
    float* k1  = (float*)(ws + 262144 + 2 * 32768);
    float* k2  = (float*)(ws + 262144 + 3 * 32768);
    float* k3  = (float*)(ws + 262144 + 4 * 32768);

    float* outp = (float*)d_out;   // f32 output

    (void)hipFuncSetAttribute((const void*)stage_kernel,
        hipFuncAttributeMaxDynamicSharedMemorySize, SMEM2);

    swizzle_w2<<<dim3(512), dim3(256), 0, stream>>>(W2, W2F);
    init_x<<<dim3(32), dim3(256), 0, stream>>>(inputs, xA);

    float* xc = xA;
    float* xn = xB;
    for (int step = 0; step < NSTEP; ++step) {
        float* kprevs[4] = { xc, k1, k2, k3 };   // kprev per stage (xc unused at s0)
        float* kouts[4]  = { k1, k2, k3, k3 };   // kout per stage (s3 -> tail path)
        for (int s = 0; s < 4; ++s) {
            stage_kernel<<<dim3(512), dim3(256), SMEM2, stream>>>(s, step,
                edges, W1, b1, W2F, b2,
                Wo1, bo1, Wo2, bo2, Wo3, bo3, ts, scp, xc, kprevs[s],
                kouts[s], k1, k2, k3, xn, outp);
        }
        float* t = xc; xc = xn; xn = t;
    }
}

// Round 8
// 1590.282 us; speedup vs baseline: 1.3989x; 1.3821x over previous
//
#include <hip/hip_runtime.h>

// Problem constants (fixed by setup_inputs)
#define BB 32
#define NN 64
#define TT 11
#define FF 4
#define KK 2
#define EE 4032      // N*(N-1)
#define NSTEP 10

typedef _Float16 f16x8 __attribute__((ext_vector_type(8)));
typedef float    f32x4v __attribute__((ext_vector_type(4)));

// ---- fused kernel LDS (v5 geometry: 512 thr, 8 receivers, grid 256 = 1 block/CU) ----
// phase C: u dbuf [2][64][512B XOR-swz] 64K | vbh dbuf [2][8][256]f16 8K |
//          y [64][4]f32 1K | wgt [2][8][64]f32 4K | agg [8][256]f32 8K
// phase D aliases the u region: augH [16][296]f16 9472 | P1H [16][264]f16 8448 |
//          P2 [16][256]f32 16384  (total 34304 < 65536)
#define OFF_U0   0
#define OFF_VB   65536
#define OFF_Y    73728
#define OFF_WGT  74752
#define OFF_AGG  78848
#define SMEM2    87040
#define OFF_AUGH 0
#define OFF_P1H  9472
#define OFF_P2   17920

__device__ __forceinline__ float scrub(float v) {
    return fminf(fmaxf(v, -3.0e4f), 3.0e4f);   // inactive when correct (|x| <~ 600)
}

__device__ __forceinline__ float load_dt(const float* ts, const void* scp, int step) {
    float t0 = ts[step], t1 = ts[step + 1];
    int w = ((const int*)scp)[0];
    float scl;
    if (w > 0 && w < 1000000) scl = (float)w;            // int32 (live path)
    else {
        float f = __int_as_float(w);
        scl = (f > 0.5f && f < 1.0e6f) ? f : 10.0f;
    }
    return (t1 - t0) / scl;
}

// u-build (512 thr): u[s][h] = sum_f y_s[f] * W1send[k][f][h], f16, XOR-swizzled rows.
__device__ __forceinline__ void build_uk(char* smem, int buf, int k, int tid,
    const float* __restrict__ W1g, const float* smY)
{
    int hg = tid & 31, sb = tid >> 5;          // sb = 0..15
    const float* w1p = W1g + k * 2048 + hg * 8;
    f32x4v wA[4], wB[4];
    #pragma unroll
    for (int f = 0; f < 4; ++f) {
        wA[f] = *(const f32x4v*)(w1p + f * 256);
        wB[f] = *(const f32x4v*)(w1p + f * 256 + 4);
    }
    const int swz = (hg * 16) ^ ((sb & 7) << 4);   // s&7 == sb&7 (it*16 ≡ 0 mod 8)
    char* ub = smem + OFF_U0 + buf * 32768;
    #pragma unroll
    for (int it = 0; it < 4; ++it) {
        int s = sb + it * 16;
        f32x4v yv = *(const f32x4v*)(smY + s * 4);
        f16x8 uv;
        #pragma unroll
        for (int e = 0; e < 4; ++e) {
            float vA = yv[0]*wA[0][e] + yv[1]*wA[1][e] + yv[2]*wA[2][e] + yv[3]*wA[3][e];
            float vB = yv[0]*wB[0][e] + yv[1]*wB[1][e] + yv[2]*wB[2][e] + yv[3]*wB[3][e];
            uv[e]     = (_Float16)vA;
            uv[e + 4] = (_Float16)vB;
        }
        *(f16x8*)(ub + s * 512 + swz) = uv;
    }
}

// vbh[buf][rv][h] = f16( b1 + sum_f y_recv[f] * W1recv[k][f][h] ), rv = 0..7
__device__ __forceinline__ void build_vbh(_Float16* smVBH, int buf, int k, int tid, int r0,
    const float* __restrict__ W1g, const float* __restrict__ b1g, const float* smY)
{
    #pragma unroll
    for (int it = 0; it < 4; ++it) {
        int i = tid + it * 512;
        int rv = i >> 8, h = i & 255;
        float acch = b1g[k * 256 + h];
        #pragma unroll
        for (int f = 0; f < 4; ++f)
            acch += smY[(r0 + rv) * 4 + f] * W1g[k * 2048 + (4 + f) * 256 + h];
        smVBH[buf * 2048 + i] = (_Float16)acch;
    }
}

// One GEMM pass: 128 rows (pair p: 2 receivers x 64 senders) x 64 cols (quarter q),
// one k. Accumulates relu(acc)*w into smAgg (k==0 stores, k==1 adds).
__device__ __forceinline__ void gemm_pass(char* smem, int buf, int k, int q, int p,
    const _Float16* __restrict__ W2F, const float* __restrict__ b2g,
    const float* smWgt, float* smAgg,
    int lane, int ln15, int lg, const int* uoff, int xm6)
{
    const _Float16* smVBH = (const _Float16*)(smem + OFF_VB);

    float bv[4];
    #pragma unroll
    for (int ni = 0; ni < 4; ++ni)
        bv[ni] = b2g[k * 256 + q * 64 + ni * 16 + ln15];

    f32x4v acc[8][4];         // b2 folded into init
    #pragma unroll
    for (int mi = 0; mi < 8; ++mi)
        #pragma unroll
        for (int ni = 0; ni < 4; ++ni)
            acc[mi][ni] = (f32x4v){bv[ni], bv[ni], bv[ni], bv[ni]};

    const _Float16* bbase = W2F + ((size_t)((k * 16 + q * 4) * 8)) * 512 + lane * 8;
    const char* ubase = smem + OFF_U0 + buf * 32768;
    const char* vbase = (const char*)(smVBH + buf * 2048 + p * 512);  // rows p*2, p*2+1

    #pragma unroll
    for (int kc = 0; kc < 8; ++kc) {
        f16x8 bfr[4];
        #pragma unroll
        for (int ni = 0; ni < 4; ++ni)
            bfr[ni] = *(const f16x8*)(bbase + (size_t)(ni * 8 + kc) * 512);
        f16x8 vbA = *(const f16x8*)(vbase + (kc * 32 + lg * 8) * 2);
        f16x8 vbB = *(const f16x8*)(vbase + (256 + kc * 32 + lg * 8) * 2);
        const int kco = (kc * 64) ^ xm6;
        f16x8 af[8];
        f16x8 z = {};
        #pragma unroll
        for (int mi = 0; mi < 8; ++mi) {
            f16x8 uv = *(const f16x8*)(ubase + uoff[mi] + kco);
            af[mi] = __builtin_elementwise_max(uv + (mi < 4 ? vbA : vbB), z);
        }
        __builtin_amdgcn_s_setprio(1);
        #pragma unroll
        for (int mi = 0; mi < 8; ++mi)
            #pragma unroll
            for (int ni = 0; ni < 4; ++ni)
                acc[mi][ni] = __builtin_amdgcn_mfma_f32_16x16x32_f16(
                    af[mi], bfr[ni], acc[mi][ni], 0, 0, 0);
        __builtin_amdgcn_s_setprio(0);
    }

    // ---- epilogue: relu * edge_w, reduce, accumulate into smAgg ----
    float rsum[2][4];
    #pragma unroll
    for (int rl = 0; rl < 2; ++rl)
        #pragma unroll
        for (int ni = 0; ni < 4; ++ni) rsum[rl][ni] = 0.0f;

    #pragma unroll
    for (int mi = 0; mi < 8; ++mi) {
        int rl = mi >> 2;
        #pragma unroll
        for (int rr = 0; rr < 4; ++rr) {
            // C/D: col = lane&15, row = (lane>>4)*4 + rr  [m89/m91]; sender s = (mi&3)*16 + row
            float w = smWgt[k * 512 + (p * 2 + rl) * 64 + (mi & 3) * 16 + lg * 4 + rr];
            #pragma unroll
            for (int ni = 0; ni < 4; ++ni)
                rsum[rl][ni] += fmaxf(acc[mi][ni][rr], 0.0f) * w;
        }
    }
    #pragma unroll
    for (int rl = 0; rl < 2; ++rl)
        #pragma unroll
        for (int ni = 0; ni < 4; ++ni) {
            rsum[rl][ni] += __shfl_xor(rsum[rl][ni], 16, 64);
            rsum[rl][ni] += __shfl_xor(rsum[rl][ni], 32, 64);
        }
    if (lane < 16) {
        #pragma unroll
        for (int rl = 0; rl < 2; ++rl)
            #pragma unroll
            for (int ni = 0; ni < 4; ++ni) {
                int idx = (p * 2 + rl) * 256 + q * 64 + ni * 16 + ln15;
                float v = rsum[rl][ni];
                if (k) v += smAgg[idx];
                smAgg[idx] = v;
            }
    }
}

// Fused per-stage kernel: edge-GEMM + aggregation + node MLP + RK4 tail.
// v8: phase C = v5 verbatim (best verified, 2161 us total). Phase D rewritten as
// f16 MFMA: aug [16x288] A-tile in LDS, Wo1F/Wo2F fragment-major f16 streamed from
// L2 as b128 (same pattern as W2F) -> replaces ~520 latency-serial scalar loads +
// ~2000 VALU FMAs per thread with 34 MFMAs per wave.
__global__ __launch_bounds__(512, 2)
void stage_kernel(int stage, int step,
    const float* __restrict__ edges, const float* __restrict__ W1g,
    const float* __restrict__ b1g,   const _Float16* __restrict__ W2F,
    const float* __restrict__ b2g,
    const _Float16* __restrict__ Wo1F, const float* __restrict__ bo1,
    const _Float16* __restrict__ Wo2F, const float* __restrict__ bo2,
    const float* __restrict__ Wo3, const float* __restrict__ bo3,
    const float* __restrict__ ts,  const void* __restrict__ scp,
    const float* __restrict__ xcur, const float* __restrict__ kprev,
    float* __restrict__ kout,
    const float* __restrict__ k1b, const float* __restrict__ k2b,
    const float* __restrict__ k3b,
    float* __restrict__ xnext, float* __restrict__ outp)
{
    extern __shared__ char smem[];
    _Float16* smVBH = (_Float16*)(smem + OFF_VB);
    float*  smY   = (float*)(smem + OFF_Y);
    float*  smWgt = (float*)(smem + OFF_WGT);
    float*  smAgg = (float*)(smem + OFF_AGG);

    const int tid = threadIdx.x;
    const int b   = blockIdx.x >> 3;
    const int rg  = blockIdx.x & 7;
    const int r0  = rg * 8;

    const float dt = load_dt(ts, scp, step);
    const float cc = (stage == 0) ? 0.0f : ((stage == 3) ? 1.0f : 0.5f);

    // ---- P0: y (all 64 nodes), edge weights (sender-major) ----
    if (tid < 256) {
        int gi = (b * NN) * FF + tid;           // tid = n*4+f
        float y = xcur[gi];
        if (stage != 0) y += cc * dt * kprev[gi];
        smY[tid] = scrub(y);
    }
    #pragma unroll
    for (int it = 0; it < 2; ++it) {
        // smWgt[k][rv][s] ; diagonal s==r -> 0
        int i = tid + it * 512;
        int k = i >> 9, m = i & 511;
        int rv = m >> 6, s = m & 63;
        int r = r0 + rv;
        float w = 0.0f;
        if (s != r) {
            int j = s - (s > r ? 1 : 0);
            w = edges[((size_t)b * EE + r * 63 + j) * KK + k];
        }
        smWgt[i] = w;
    }

    const int lane = tid & 63;
    const int wn   = tid >> 6;    // 8 waves: p = wn>>1 (receiver pair 0..3), ch = wn&1 (col half)
    const int p    = wn >> 1;
    const int ch   = wn & 1;
    const int ln15 = lane & 15;
    const int lg   = lane >> 4;   // 0..3

    // swizzled u read offsets: byte = s*512 + ((kc*64 + lg*16) ^ ((s&7)<<4)),
    // s = (mi&3)*16 + ln15 -> s&7 = ln15&7 (per-lane constant).
    const int xm45 = (ln15 & 3) << 4;
    const int xm6  = (ln15 & 4) << 4;
    int uoff[8];
    #pragma unroll
    for (int mi = 0; mi < 8; ++mi) {
        int s = (mi & 3) * 16 + ln15;
        uoff[mi] = s * 512 + ((lg * 16) ^ xm45);
    }

    __syncthreads();              // smY/smWgt ready

    // ---- build k=0 into buf0 ----
    build_uk(smem, 0, 0, tid, W1g, smY);
    build_vbh(smVBH, 0, 0, tid, r0, W1g, b1g, smY);
    __syncthreads();              // u0/vbh0 ready

    // ---- build k=1 (VALU) interleaves with GEMM k=0 (MFMA) ----
    build_uk(smem, 1, 1, tid, W1g, smY);
    build_vbh(smVBH, 1, 1, tid, r0, W1g, b1g, smY);
    gemm_pass(smem, 0, 0, ch * 2 + 0, p, W2F, b2g, smWgt, smAgg, lane, ln15, lg, uoff, xm6);
    gemm_pass(smem, 0, 0, ch * 2 + 1, p, W2F, b2g, smWgt, smAgg, lane, ln15, lg, uoff, xm6);
    __syncthreads();              // u1/vbh1 ready
    gemm_pass(smem, 1, 1, ch * 2 + 0, p, W2F, b2g, smWgt, smAgg, lane, ln15, lg, uoff, xm6);
    gemm_pass(smem, 1, 1, ch * 2 + 1, p, W2F, b2g, smWgt, smAgg, lane, ln15, lg, uoff, xm6);
    __syncthreads();              // smAgg complete; u region free for aliasing

    // ======== phase D: node MLP via f16 MFMA (rows r0..r0+7) ========
    _Float16* smAugH = (_Float16*)(smem + OFF_AUGH);  // [16][296] (288 used)
    _Float16* smP1H  = (_Float16*)(smem + OFF_P1H);   // [16][264] (256 used)
    float*    smP2   = (float*)(smem + OFF_P2);       // [16][256]

    // aug16: rows 0..7 = [y(4) | agg(256) | 0 pad], rows 8..15 = 0
    for (int i = tid; i < 16 * 148; i += 512) {
        int row = i / 148, cp = (i - row * 148) * 2;
        float f0 = 0.0f, f1 = 0.0f;
        if (row < 8) {
            f0 = (cp < 4) ? smY[(r0 + row) * 4 + cp]
               : (cp < 260 ? smAgg[row * 256 + cp - 4] : 0.0f);
            int c1 = cp + 1;
            f1 = (c1 < 4) ? smY[(r0 + row) * 4 + c1]
               : (c1 < 260 ? smAgg[row * 256 + c1 - 4] : 0.0f);
        }
        smAugH[row * 296 + cp]     = (_Float16)f0;
        smAugH[row * 296 + cp + 1] = (_Float16)f1;
    }
    __syncthreads();

    const int ot0 = wn * 2, ot1 = ot0 + 1;   // each wave owns two 16-col tiles

    // ---- L1: aug16 @ Wo1F (K=288, 9 k-tiles) + bo1, relu -> P1H f16 ----
    {
        float b0 = bo1[ot0 * 16 + ln15], b1v = bo1[ot1 * 16 + ln15];
        f32x4v a0 = {b0, b0, b0, b0}, a1 = {b1v, b1v, b1v, b1v};
        const _Float16* bb0 = Wo1F + (size_t)(ot0 * 9) * 512 + lane * 8;
        const _Float16* bb1 = Wo1F + (size_t)(ot1 * 9) * 512 + lane * 8;
        #pragma unroll
        for (int kc = 0; kc < 9; ++kc) {
            f16x8 av  = *(const f16x8*)(smAugH + ln15 * 296 + kc * 32 + lg * 8);
            f16x8 bf0 = *(const f16x8*)(bb0 + kc * 512);
            f16x8 bf1 = *(const f16x8*)(bb1 + kc * 512);
            a0 = __builtin_amdgcn_mfma_f32_16x16x32_f16(av, bf0, a0, 0, 0, 0);
            a1 = __builtin_amdgcn_mfma_f32_16x16x32_f16(av, bf1, a1, 0, 0, 0);
        }
        #pragma unroll
        for (int rr = 0; rr < 4; ++rr) {
            int row = lg * 4 + rr;            // C/D: col = lane&15, row = lg*4+rr
            smP1H[row * 264 + ot0 * 16 + ln15] = (_Float16)fmaxf(a0[rr], 0.0f);
            smP1H[row * 264 + ot1 * 16 + ln15] = (_Float16)fmaxf(a1[rr], 0.0f);
        }
    }
    __syncthreads();
    // ---- L2: P1 @ Wo2F (K=256, 8 k-tiles) + bo2, relu -> P2 f32 ----
    {
        float b0 = bo2[ot0 * 16 + ln15], b1v = bo2[ot1 * 16 + ln15];
        f32x4v a0 = {b0, b0, b0, b0}, a1 = {b1v, b1v, b1v, b1v};
        const _Float16* bb0 = Wo2F + (size_t)(ot0 * 8) * 512 + lane * 8;
        const _Float16* bb1 = Wo2F + (size_t)(ot1 * 8) * 512 + lane * 8;
        #pragma unroll
        for (int kc = 0; kc < 8; ++kc) {
            f16x8 av  = *(const f16x8*)(smP1H + ln15 * 264 + kc * 32 + lg * 8);
            f16x8 bf0 = *(const f16x8*)(bb0 + kc * 512);
            f16x8 bf1 = *(const f16x8*)(bb1 + kc * 512);
            a0 = __builtin_amdgcn_mfma_f32_16x16x32_f16(av, bf0, a0, 0, 0, 0);
            a1 = __builtin_amdgcn_mfma_f32_16x16x32_f16(av, bf1, a1, 0, 0, 0);
        }
        #pragma unroll
        for (int rr = 0; rr < 4; ++rr) {
            int row = lg * 4 + rr;
            smP2[row * 256 + ot0 * 16 + ln15] = fmaxf(a0[rr], 0.0f);
            smP2[row * 256 + ot1 * 16 + ln15] = fmaxf(a1[rr], 0.0f);
        }
    }
    __syncthreads();
    // ---- L3 (256 -> 4) + residual + RK4 tail ----
    {
        int rr = tid >> 6, f = (tid >> 4) & 3, hs = tid & 15;   // one wave per row, 8 rows
        float part = 0.0f;
        #pragma unroll
        for (int j = 0; j < 16; ++j) {
            int h = hs + j * 16;
            part += smP2[rr * 256 + h] * Wo3[h * 4 + f];
        }
        part += __shfl_xor(part, 8, 64);
        part += __shfl_xor(part, 4, 64);
        part += __shfl_xor(part, 2, 64);
        part += __shfl_xor(part, 1, 64);
        if (hs == 0) {
            int grow = b * NN + r0 + rr;
            int gi   = grow * 4 + f;
            float y = smY[(r0 + rr) * 4 + f];
            float knew = scrub(y + bo3[f] + part);    // f(y) = y + p
            if (stage < 3) {
                kout[gi] = knew;
            } else {
                float xn = scrub(xcur[gi] + (dt * (1.0f / 6.0f)) *
                           (k1b[gi] + 2.0f * k2b[gi] + 2.0f * k3b[gi] + knew));
                xnext[gi] = xn;
                // out layout (B, N, NSTEP, F): row = b*64+n
                outp[(size_t)grow * NSTEP * FF + step * FF + f] = xn;
            }
        }
    }
}

// Pre-swizzle W2 -> fragment-major W2F (verified): chunk (k,ot,kc) is
// 1 KiB; lane l holds B[o = ot*16 + (l&15)][h = kc*32 + (l>>4)*8 + e]
__global__ void swizzle_w2(const float* __restrict__ W2, _Float16* __restrict__ W2F)
{
    int idx = blockIdx.x * 256 + threadIdx.x;       // 0 .. 131071
    int k   = idx >> 16;
    int rem = idx & 65535;
    int ch  = rem >> 9;
    int pos = rem & 511;
    int ot  = ch >> 3, kc = ch & 7;
    int l   = pos >> 3, e = pos & 7;
    int o   = ot * 16 + (l & 15);
    int h   = kc * 32 + (l >> 4) * 8 + e;
    W2F[idx] = (_Float16)W2[(size_t)(k * 256 + h) * 256 + o];
}

// Wo1 [260][256] -> fragment-major f16, K padded to 288 (zeros).
__global__ void swizzle_wo1(const float* __restrict__ Wo1, _Float16* __restrict__ Wo1F)
{
    int idx = blockIdx.x * 256 + threadIdx.x;       // 0 .. 73727
    int ch = idx >> 9, pos = idx & 511;
    int ot = ch / 9, kc = ch - ot * 9;
    int l = pos >> 3, e = pos & 7;
    int k = kc * 32 + (l >> 4) * 8 + e;
    int o = ot * 16 + (l & 15);
    Wo1F[idx] = (k < 260) ? (_Float16)Wo1[(size_t)k * 256 + o] : (_Float16)0.0f;
}

// Wo2 [256][256] -> fragment-major f16.
__global__ void swizzle_wo2(const float* __restrict__ Wo2, _Float16* __restrict__ Wo2F)
{
    int idx = blockIdx.x * 256 + threadIdx.x;       // 0 .. 65535
    int ch = idx >> 9, pos = idx & 511;
    int ot = ch >> 3, kc = ch & 7;
    int l = pos >> 3, e = pos & 7;
    int k = kc * 32 + (l >> 4) * 8 + e;
    int o = ot * 16 + (l & 15);
    Wo2F[idx] = (_Float16)Wo2[(size_t)k * 256 + o];
}

__global__ void init_x(const float* __restrict__ inp, float* __restrict__ x0)
{
    int i = blockIdx.x * 256 + threadIdx.x;   // i = (b*64+n)*4+f
    if (i < BB * NN * FF) {
        int f = i & 3, bn = i >> 2;
        x0[i] = scrub(inp[(size_t)(bn * TT) * FF + f]);   // inputs[b][n][0][f]
    }
}

static int find_input(const int* in_sizes, int n_in, int want, unsigned char* used, int dflt) {
    if (dflt >= 0 && dflt < n_in && in_sizes[dflt] == want && !used[dflt]) { used[dflt] = 1; return dflt; }
    for (int i = 0; i < n_in; ++i)
        if (!used[i] && in_sizes[i] == want) { used[i] = 1; return i; }
    return dflt;
}

extern "C" void kernel_launch(void* const* d_in, const int* in_sizes, int n_in,
                              void* d_out, int out_size, void* d_ws, size_t ws_size,
                              hipStream_t stream)
{
    unsigned char used[64] = {0};
    int iInp = find_input(in_sizes, n_in, BB*NN*TT*FF, used, 0);
    int iEdg = find_input(in_sizes, n_in, BB*EE*KK,    used, 1);
    (void)find_input(in_sizes, n_in, EE*NN, used, 2);              // rel_rec (unused)
    (void)find_input(in_sizes, n_in, EE*NN, used, 3);              // rel_send (unused)
    int iW1  = find_input(in_sizes, n_in, KK*8*256,  used, 4);
    int ib1  = find_input(in_sizes, n_in, KK*256,    used, 5);
    int iW2  = find_input(in_sizes, n_in, KK*256*256,used, 6);
    int ib2  = find_input(in_sizes, n_in, KK*256,    used, 7);
    int iWo1 = find_input(in_sizes, n_in, 260*256,   used, 8);
    int ibo1 = find_input(in_sizes, n_in, 256,       used, 9);
    int iWo2 = find_input(in_sizes, n_in, 256*256,   used, 10);
    int ibo2 = find_input(in_sizes, n_in, 256,       used, 11);
    int iWo3 = find_input(in_sizes, n_in, 256*4,     used, 12);
    int ibo3 = find_input(in_sizes, n_in, 4,         used, 13);
    int iTs  = find_input(in_sizes, n_in, TT,        used, 14);
    (void)find_input(in_sizes, n_in, 1, used, 15);                 // pred_steps
    int iSc  = find_input(in_sizes, n_in, 1,         used, 16);    // scale

    const float* inputs = (const float*)d_in[iInp];
    const float* edges  = (const float*)d_in[iEdg];
    const float* W1  = (const float*)d_in[iW1];
    const float* b1  = (const float*)d_in[ib1];
    const float* W2  = (const float*)d_in[iW2];
    const float* b2  = (const float*)d_in[ib2];
    const float* Wo1 = (const float*)d_in[iWo1];
    const float* bo1 = (const float*)d_in[ibo1];
    const float* Wo2 = (const float*)d_in[iWo2];
    const float* bo2 = (const float*)d_in[ibo2];
    const float* Wo3 = (const float*)d_in[iWo3];
    const float* bo3 = (const float*)d_in[ibo3];
    const float* ts  = (const float*)d_in[iTs];
    const void*  scp = d_in[iSc];

    char* ws = (char*)d_ws;
    _Float16* W2F  = (_Float16*)ws;                       // 262144 B
    _Float16* Wo1F = (_Float16*)(ws + 262144);            // 147456 B
    _Float16* Wo2F = (_Float16*)(ws + 409600);            // 131072 B
    float* xA  = (float*)(ws + 540672);
    float* xB  = (float*)(ws + 540672 + 1 * 32768);
    float* k1  = (float*)(ws + 540672 + 2 * 32768);
    float* k2  = (float*)(ws + 540672 + 3 * 32768);
    float* k3  = (float*)(ws + 540672 + 4 * 32768);

    float* outp = (float*)d_out;   // f32 output

    (void)hipFuncSetAttribute((const void*)stage_kernel,
        hipFuncAttributeMaxDynamicSharedMemorySize, SMEM2);

    swizzle_w2<<<dim3(512), dim3(256), 0, stream>>>(W2, W2F);
    swizzle_wo1<<<dim3(288), dim3(256), 0, stream>>>(Wo1, Wo1F);
    swizzle_wo2<<<dim3(256), dim3(256), 0, stream>>>(Wo2, Wo2F);
    init_x<<<dim3(32), dim3(256), 0, stream>>>(inputs, xA);

    float* xc = xA;
    float* xn = xB;
    for (int step = 0; step < NSTEP; ++step) {
        float* kprevs[4] = { xc, k1, k2, k3 };   // kprev per stage (xc unused at s0)
        float* kouts[4]  = { k1, k2, k3, k3 };   // kout per stage (s3 -> tail path)
        for (int s = 0; s < 4; ++s) {
            stage_kernel<<<dim3(256), dim3(512), SMEM2, stream>>>(s, step,
                edges, W1, b1, W2F, b2,
                Wo1F, bo1, Wo2F, bo2, Wo3, bo3, ts, scp, xc, kprevs[s],
                kouts[s], k1, k2, k3, xn, outp);
        }
        float* t = xc; xc = xn; xn = t;
    }
}

// Round 9
// 1535.354 us; speedup vs baseline: 1.4490x; 1.0358x over previous
//
#include <hip/hip_runtime.h>

// Problem constants (fixed by setup_inputs)
#define BB 32
#define NN 64
#define TT 11
#define FF 4
#define KK 2
#define EE 4032      // N*(N-1)
#define NSTEP 10

typedef _Float16 f16x8 __attribute__((ext_vector_type(8)));
typedef float    f32x4v __attribute__((ext_vector_type(4)));

// ---- fused kernel LDS (512 thr, 8 receivers, grid 256 = 1 block/CU) ----
// phase C: u dbuf [2][64][512B XOR-swz] 64K | vbh dbuf [2][8][256]f16 8K |
//          y [64][4]f32 1K | wgt [2][8][64]f32 4K
// phase D aliases the (dead) u region: augH [16][296]f16 9472 | P1H [16][264]f16 8448 |
//          P2 [16][256]f32 16384  (total 34304 < 65536)
#define OFF_U0   0
#define OFF_VB   65536
#define OFF_Y    73728
#define OFF_WGT  74752
#define SMEM2    78848
#define OFF_AUGH 0
#define OFF_P1H  9472
#define OFF_P2   17920

__device__ __forceinline__ float scrub(float v) {
    return fminf(fmaxf(v, -3.0e4f), 3.0e4f);   // inactive when correct (|x| <~ 600)
}

__device__ __forceinline__ float load_dt(const float* ts, const void* scp, int step) {
    float t0 = ts[step], t1 = ts[step + 1];
    int w = ((const int*)scp)[0];
    float scl;
    if (w > 0 && w < 1000000) scl = (float)w;            // int32 (live path)
    else {
        float f = __int_as_float(w);
        scl = (f > 0.5f && f < 1.0e6f) ? f : 10.0f;
    }
    return (t1 - t0) / scl;
}

// u-build (512 thr): u[s][h] = sum_f y_s[f] * W1send[k][f][h], f16, XOR-swizzled rows.
__device__ __forceinline__ void build_uk(char* smem, int buf, int k, int tid,
    const float* __restrict__ W1g, const float* smY)
{
    int hg = tid & 31, sb = tid >> 5;          // sb = 0..15
    const float* w1p = W1g + k * 2048 + hg * 8;
    f32x4v wA[4], wB[4];
    #pragma unroll
    for (int f = 0; f < 4; ++f) {
        wA[f] = *(const f32x4v*)(w1p + f * 256);
        wB[f] = *(const f32x4v*)(w1p + f * 256 + 4);
    }
    const int swz = (hg * 16) ^ ((sb & 7) << 4);   // s&7 == sb&7 (it*16 ≡ 0 mod 8)
    char* ub = smem + OFF_U0 + buf * 32768;
    #pragma unroll
    for (int it = 0; it < 4; ++it) {
        int s = sb + it * 16;
        f32x4v yv = *(const f32x4v*)(smY + s * 4);
        f16x8 uv;
        #pragma unroll
        for (int e = 0; e < 4; ++e) {
            float vA = yv[0]*wA[0][e] + yv[1]*wA[1][e] + yv[2]*wA[2][e] + yv[3]*wA[3][e];
            float vB = yv[0]*wB[0][e] + yv[1]*wB[1][e] + yv[2]*wB[2][e] + yv[3]*wB[3][e];
            uv[e]     = (_Float16)vA;
            uv[e + 4] = (_Float16)vB;
        }
        *(f16x8*)(ub + s * 512 + swz) = uv;
    }
}

// vbh[buf][rv][h] = f16( b1 + sum_f y_recv[f] * W1recv[k][f][h] ), rv = 0..7
__device__ __forceinline__ void build_vbh(_Float16* smVBH, int buf, int k, int tid, int r0,
    const float* __restrict__ W1g, const float* __restrict__ b1g, const float* smY)
{
    #pragma unroll
    for (int it = 0; it < 4; ++it) {
        int i = tid + it * 512;
        int rv = i >> 8, h = i & 255;
        float acch = b1g[k * 256 + h];
        #pragma unroll
        for (int f = 0; f < 4; ++f)
            acch += smY[(r0 + rv) * 4 + f] * W1g[k * 2048 + (4 + f) * 256 + h];
        smVBH[buf * 2048 + i] = (_Float16)acch;
    }
}

// One GEMM half-pass: wave owns ONE receiver rv; 64 sender-rows (4 mi) x 128 cols
// (col-half ch2), one k. Per kc: 4 u-reads + 1 vb-read feed 32 MFMAs (u duplication
// of the old pair layout removed -> LDS b128 reads halved). relu(acc)*w accumulated
// into rsum[8] registers (across both k; no LDS agg round-trip).
__device__ __forceinline__ void gemm_half(char* smem, int buf, int k, int rv, int ch2,
    const _Float16* __restrict__ W2F, const float* __restrict__ b2g,
    const float* smWgt,
    int lane, int ln15, int lg, const int* uoff, int xm6,
    float rsum[8])
{
    const _Float16* smVBH = (const _Float16*)(smem + OFF_VB);

    float bv[8];
    #pragma unroll
    for (int ni = 0; ni < 8; ++ni)
        bv[ni] = b2g[k * 256 + ch2 * 128 + ni * 16 + ln15];

    f32x4v acc[4][8];         // b2 folded into init; 128 AGPR
    #pragma unroll
    for (int mi = 0; mi < 4; ++mi)
        #pragma unroll
        for (int ni = 0; ni < 8; ++ni)
            acc[mi][ni] = (f32x4v){bv[ni], bv[ni], bv[ni], bv[ni]};

    const _Float16* bbase = W2F + ((size_t)((k * 16 + ch2 * 8) * 8)) * 512 + lane * 8;
    const char* ubase = smem + OFF_U0 + buf * 32768;
    const _Float16* vbase = smVBH + buf * 2048 + rv * 256;

    #pragma unroll
    for (int kc = 0; kc < 8; ++kc) {
        f16x8 bfr[8];
        #pragma unroll
        for (int ni = 0; ni < 8; ++ni)
            bfr[ni] = *(const f16x8*)(bbase + (size_t)(ni * 8 + kc) * 512);
        f16x8 vbv = *(const f16x8*)(vbase + kc * 32 + lg * 8);
        const int kco = (kc * 64) ^ xm6;
        f16x8 af[4];
        f16x8 z = {};
        #pragma unroll
        for (int mi = 0; mi < 4; ++mi) {
            f16x8 uv = *(const f16x8*)(ubase + uoff[mi] + kco);
            af[mi] = __builtin_elementwise_max(uv + vbv, z);
        }
        __builtin_amdgcn_s_setprio(1);
        #pragma unroll
        for (int mi = 0; mi < 4; ++mi)
            #pragma unroll
            for (int ni = 0; ni < 8; ++ni)
                acc[mi][ni] = __builtin_amdgcn_mfma_f32_16x16x32_f16(
                    af[mi], bfr[ni], acc[mi][ni], 0, 0, 0);
        __builtin_amdgcn_s_setprio(0);
    }

    // ---- epilogue: relu * edge_w into rsum regs ----
    #pragma unroll
    for (int mi = 0; mi < 4; ++mi) {
        #pragma unroll
        for (int rr = 0; rr < 4; ++rr) {
            // C/D: col = lane&15, row = lg*4 + rr  [m89/m91]; sender s = mi*16 + row
            float w = smWgt[k * 512 + rv * 64 + mi * 16 + lg * 4 + rr];
            #pragma unroll
            for (int ni = 0; ni < 8; ++ni)
                rsum[ni] += fmaxf(acc[mi][ni][rr], 0.0f) * w;
        }
    }
}

// Fused per-stage kernel: edge-GEMM + aggregation + node MLP (MFMA) + RK4 tail.
// v9: wave = (1 receiver x 128 cols) re-tile (LDS reads halved, af VALU halved),
// rsum in regs across k, agg written directly as f16 into the MLP A-tile
// (smAgg buffer + aug staging pass + one barrier deleted). Phase D = v8 MFMA MLP.
__global__ __launch_bounds__(512, 2)
void stage_kernel(int stage, int step,
    const float* __restrict__ edges, const float* __restrict__ W1g,
    const float* __restrict__ b1g,   const _Float16* __restrict__ W2F,
    const float* __restrict__ b2g,
    const _Float16* __restrict__ Wo1F, const float* __restrict__ bo1,
    const _Float16* __restrict__ Wo2F, const float* __restrict__ bo2,
    const float* __restrict__ Wo3, const float* __restrict__ bo3,
    const float* __restrict__ ts,  const void* __restrict__ scp,
    const float* __restrict__ xcur, const float* __restrict__ kprev,
    float* __restrict__ kout,
    const float* __restrict__ k1b, const float* __restrict__ k2b,
    const float* __restrict__ k3b,
    float* __restrict__ xnext, float* __restrict__ outp)
{
    extern __shared__ char smem[];
    _Float16* smVBH = (_Float16*)(smem + OFF_VB);
    float*  smY   = (float*)(smem + OFF_Y);
    float*  smWgt = (float*)(smem + OFF_WGT);

    const int tid = threadIdx.x;
    const int b   = blockIdx.x >> 3;
    const int rg  = blockIdx.x & 7;
    const int r0  = rg * 8;

    const float dt = load_dt(ts, scp, step);
    const float cc = (stage == 0) ? 0.0f : ((stage == 3) ? 1.0f : 0.5f);

    // ---- P0: y (all 64 nodes), edge weights (sender-major) ----
    if (tid < 256) {
        int gi = (b * NN) * FF + tid;           // tid = n*4+f
        float y = xcur[gi];
        if (stage != 0) y += cc * dt * kprev[gi];
        smY[tid] = scrub(y);
    }
    #pragma unroll
    for (int it = 0; it < 2; ++it) {
        // smWgt[k][rv][s] ; diagonal s==r -> 0
        int i = tid + it * 512;
        int k = i >> 9, m = i & 511;
        int rv = m >> 6, s = m & 63;
        int r = r0 + rv;
        float w = 0.0f;
        if (s != r) {
            int j = s - (s > r ? 1 : 0);
            w = edges[((size_t)b * EE + r * 63 + j) * KK + k];
        }
        smWgt[i] = w;
    }

    const int lane = tid & 63;
    const int wn   = tid >> 6;    // 8 waves: wave wn owns receiver rv = wn
    const int rv   = wn;
    const int ln15 = lane & 15;
    const int lg   = lane >> 4;   // 0..3

    // swizzled u read offsets: byte = s*512 + ((kc*64 + lg*16) ^ ((s&7)<<4)),
    // s = mi*16 + ln15 -> s&7 = ln15&7 (per-lane constant).
    const int xm45 = (ln15 & 3) << 4;
    const int xm6  = (ln15 & 4) << 4;
    int uoff[4];
    #pragma unroll
    for (int mi = 0; mi < 4; ++mi) {
        int s = mi * 16 + ln15;
        uoff[mi] = s * 512 + ((lg * 16) ^ xm45);
    }

    float rsA[8], rsB[8];         // col-half 0 / 1, accumulated across k
    #pragma unroll
    for (int ni = 0; ni < 8; ++ni) { rsA[ni] = 0.0f; rsB[ni] = 0.0f; }

    __syncthreads();              // smY/smWgt ready

    // ---- build k=0 into buf0 ----
    build_uk(smem, 0, 0, tid, W1g, smY);
    build_vbh(smVBH, 0, 0, tid, r0, W1g, b1g, smY);
    __syncthreads();              // u0/vbh0 ready

    // ---- build k=1 (VALU) interleaves with GEMM k=0 (MFMA) ----
    build_uk(smem, 1, 1, tid, W1g, smY);
    build_vbh(smVBH, 1, 1, tid, r0, W1g, b1g, smY);
    gemm_half(smem, 0, 0, rv, 0, W2F, b2g, smWgt, lane, ln15, lg, uoff, xm6, rsA);
    gemm_half(smem, 0, 0, rv, 1, W2F, b2g, smWgt, lane, ln15, lg, uoff, xm6, rsB);
    __syncthreads();              // u1/vbh1 ready; buf0 dead from here on
    gemm_half(smem, 1, 1, rv, 0, W2F, b2g, smWgt, lane, ln15, lg, uoff, xm6, rsA);
    gemm_half(smem, 1, 1, rv, 1, W2F, b2g, smWgt, lane, ln15, lg, uoff, xm6, rsB);

    // ---- reduce over lg (senders) + write agg row directly as f16 A-tile ----
    #pragma unroll
    for (int ni = 0; ni < 8; ++ni) {
        rsA[ni] += __shfl_xor(rsA[ni], 16, 64);
        rsA[ni] += __shfl_xor(rsA[ni], 32, 64);
        rsB[ni] += __shfl_xor(rsB[ni], 16, 64);
        rsB[ni] += __shfl_xor(rsB[ni], 32, 64);
    }
    // augH aliases buf0 (dead since the mid-barrier): safe to write without a barrier.
    // rows 8..15 / cols 260..287 stay garbage (finite f16 from u) — zero-padded Wo1F
    // kills cols >=260; rows >=8 never read back (MFMA rows are independent).
    _Float16* smAugH = (_Float16*)(smem + OFF_AUGH);  // [16][296]
    if (lane < 16) {
        #pragma unroll
        for (int ni = 0; ni < 8; ++ni) {
            smAugH[rv * 296 + 4   + ni * 16 + ln15] = (_Float16)rsA[ni];
            smAugH[rv * 296 + 132 + ni * 16 + ln15] = (_Float16)rsB[ni];
        }
    } else if (lg == 1 && ln15 < 4) {
        smAugH[rv * 296 + ln15] = (_Float16)smY[(r0 + rv) * 4 + ln15];
    }
    __syncthreads();              // augH ready

    // ======== phase D: node MLP via f16 MFMA (rows r0..r0+7) ========
    _Float16* smP1H = (_Float16*)(smem + OFF_P1H);   // [16][264] (256 used)
    float*    smP2  = (float*)(smem + OFF_P2);       // [16][256]

    const int ot0 = wn * 2, ot1 = ot0 + 1;   // each wave owns two 16-col tiles

    // ---- L1: aug16 @ Wo1F (K=288, 9 k-tiles) + bo1, relu -> P1H f16 ----
    {
        float b0 = bo1[ot0 * 16 + ln15], b1v = bo1[ot1 * 16 + ln15];
        f32x4v a0 = {b0, b0, b0, b0}, a1 = {b1v, b1v, b1v, b1v};
        const _Float16* bb0 = Wo1F + (size_t)(ot0 * 9) * 512 + lane * 8;
        const _Float16* bb1 = Wo1F + (size_t)(ot1 * 9) * 512 + lane * 8;
        #pragma unroll
        for (int kc = 0; kc < 9; ++kc) {
            f16x8 av  = *(const f16x8*)(smAugH + ln15 * 296 + kc * 32 + lg * 8);
            f16x8 bf0 = *(const f16x8*)(bb0 + kc * 512);
            f16x8 bf1 = *(const f16x8*)(bb1 + kc * 512);
            a0 = __builtin_amdgcn_mfma_f32_16x16x32_f16(av, bf0, a0, 0, 0, 0);
            a1 = __builtin_amdgcn_mfma_f32_16x16x32_f16(av, bf1, a1, 0, 0, 0);
        }
        __syncthreads();          // all augH reads done before P1H (disjoint, but order waves)
        #pragma unroll
        for (int rr = 0; rr < 4; ++rr) {
            int row = lg * 4 + rr;            // C/D: col = lane&15, row = lg*4+rr
            smP1H[row * 264 + ot0 * 16 + ln15] = (_Float16)fmaxf(a0[rr], 0.0f);
            smP1H[row * 264 + ot1 * 16 + ln15] = (_Float16)fmaxf(a1[rr], 0.0f);
        }
    }
    __syncthreads();
    // ---- L2: P1 @ Wo2F (K=256, 8 k-tiles) + bo2, relu -> P2 f32 ----
    {
        float b0 = bo2[ot0 * 16 + ln15], b1v = bo2[ot1 * 16 + ln15];
        f32x4v a0 = {b0, b0, b0, b0}, a1 = {b1v, b1v, b1v, b1v};
        const _Float16* bb0 = Wo2F + (size_t)(ot0 * 8) * 512 + lane * 8;
        const _Float16* bb1 = Wo2F + (size_t)(ot1 * 8) * 512 + lane * 8;
        #pragma unroll
        for (int kc = 0; kc < 8; ++kc) {
            f16x8 av  = *(const f16x8*)(smP1H + ln15 * 264 + kc * 32 + lg * 8);
            f16x8 bf0 = *(const f16x8*)(bb0 + kc * 512);
            f16x8 bf1 = *(const f16x8*)(bb1 + kc * 512);
            a0 = __builtin_amdgcn_mfma_f32_16x16x32_f16(av, bf0, a0, 0, 0, 0);
            a1 = __builtin_amdgcn_mfma_f32_16x16x32_f16(av, bf1, a1, 0, 0, 0);
        }
        #pragma unroll
        for (int rr = 0; rr < 4; ++rr) {
            int row = lg * 4 + rr;
            smP2[row * 256 + ot0 * 16 + ln15] = fmaxf(a0[rr], 0.0f);
            smP2[row * 256 + ot1 * 16 + ln15] = fmaxf(a1[rr], 0.0f);
        }
    }
    __syncthreads();
    // ---- L3 (256 -> 4) + residual + RK4 tail ----
    {
        int rr = tid >> 6, f = (tid >> 4) & 3, hs = tid & 15;   // one wave per row, 8 rows
        float part = 0.0f;
        #pragma unroll
        for (int j = 0; j < 16; ++j) {
            int h = hs + j * 16;
            part += smP2[rr * 256 + h] * Wo3[h * 4 + f];
        }
        part += __shfl_xor(part, 8, 64);
        part += __shfl_xor(part, 4, 64);
        part += __shfl_xor(part, 2, 64);
        part += __shfl_xor(part, 1, 64);
        if (hs == 0) {
            int grow = b * NN + r0 + rr;
            int gi   = grow * 4 + f;
            float y = smY[(r0 + rr) * 4 + f];
            float knew = scrub(y + bo3[f] + part);    // f(y) = y + p
            if (stage < 3) {
                kout[gi] = knew;
            } else {
                float xn = scrub(xcur[gi] + (dt * (1.0f / 6.0f)) *
                           (k1b[gi] + 2.0f * k2b[gi] + 2.0f * k3b[gi] + knew));
                xnext[gi] = xn;
                // out layout (B, N, NSTEP, F): row = b*64+n
                outp[(size_t)grow * NSTEP * FF + step * FF + f] = xn;
            }
        }
    }
}

// Pre-swizzle W2 -> fragment-major W2F (verified): chunk (k,ot,kc) is
// 1 KiB; lane l holds B[o = ot*16 + (l&15)][h = kc*32 + (l>>4)*8 + e]
__global__ void swizzle_w2(const float* __restrict__ W2, _Float16* __restrict__ W2F)
{
    int idx = blockIdx.x * 256 + threadIdx.x;       // 0 .. 131071
    int k   = idx >> 16;
    int rem = idx & 65535;
    int ch  = rem >> 9;
    int pos = rem & 511;
    int ot  = ch >> 3, kc = ch & 7;
    int l   = pos >> 3, e = pos & 7;
    int o   = ot * 16 + (l & 15);
    int h   = kc * 32 + (l >> 4) * 8 + e;
    W2F[idx] = (_Float16)W2[(size_t)(k * 256 + h) * 256 + o];
}

// Wo1 [260][256] -> fragment-major f16, K padded to 288 (zeros).
__global__ void swizzle_wo1(const float* __restrict__ Wo1, _Float16* __restrict__ Wo1F)
{
    int idx = blockIdx.x * 256 + threadIdx.x;       // 0 .. 73727
    int ch = idx >> 9, pos = idx & 511;
    int ot = ch / 9, kc = ch - ot * 9;
    int l = pos >> 3, e = pos & 7;
    int k = kc * 32 + (l >> 4) * 8 + e;
    int o = ot * 16 + (l & 15);
    Wo1F[idx] = (k < 260) ? (_Float16)Wo1[(size_t)k * 256 + o] : (_Float16)0.0f;
}

// Wo2 [256][256] -> fragment-major f16.
__global__ void swizzle_wo2(const float* __restrict__ Wo2, _Float16* __restrict__ Wo2F)
{
    int idx = blockIdx.x * 256 + threadIdx.x;       // 0 .. 65535
    int ch = idx >> 9, pos = idx & 511;
    int ot = ch >> 3, kc = ch & 7;
    int l = pos >> 3, e = pos & 7;
    int k = kc * 32 + (l >> 4) * 8 + e;
    int o = ot * 16 + (l & 15);
    Wo2F[idx] = (_Float16)Wo2[(size_t)k * 256 + o];
}

__global__ void init_x(const float* __restrict__ inp, float* __restrict__ x0)
{
    int i = blockIdx.x * 256 + threadIdx.x;   // i = (b*64+n)*4+f
    if (i < BB * NN * FF) {
        int f = i & 3, bn = i >> 2;
        x0[i] = scrub(inp[(size_t)(bn * TT) * FF + f]);   // inputs[b][n][0][f]
    }
}

static int find_input(const int* in_sizes, int n_in, int want, unsigned char* used, int dflt) {
    if (dflt >= 0 && dflt < n_in && in_sizes[dflt] == want && !used[dflt]) { used[dflt] = 1; return dflt; }
    for (int i = 0; i < n_in; ++i)
        if (!used[i] && in_sizes[i] == want) { used[i] = 1; return i; }
    return dflt;
}

extern "C" void kernel_launch(void* const* d_in, const int* in_sizes, int n_in,
                              void* d_out, int out_size, void* d_ws, size_t ws_size,
                              hipStream_t stream)
{
    unsigned char used[64] = {0};
    int iInp = find_input(in_sizes, n_in, BB*NN*TT*FF, used, 0);
    int iEdg = find_input(in_sizes, n_in, BB*EE*KK,    used, 1);
    (void)find_input(in_sizes, n_in, EE*NN, used, 2);              // rel_rec (unused)
    (void)find_input(in_sizes, n_in, EE*NN, used, 3);              // rel_send (unused)
    int iW1  = find_input(in_sizes, n_in, KK*8*256,  used, 4);
    int ib1  = find_input(in_sizes, n_in, KK*256,    used, 5);
    int iW2  = find_input(in_sizes, n_in, KK*256*256,used, 6);
    int ib2  = find_input(in_sizes, n_in, KK*256,    used, 7);
    int iWo1 = find_input(in_sizes, n_in, 260*256,   used, 8);
    int ibo1 = find_input(in_sizes, n_in, 256,       used, 9);
    int iWo2 = find_input(in_sizes, n_in, 256*256,   used, 10);
    int ibo2 = find_input(in_sizes, n_in, 256,       used, 11);
    int iWo3 = find_input(in_sizes, n_in, 256*4,     used, 12);
    int ibo3 = find_input(in_sizes, n_in, 4,         used, 13);
    int iTs  = find_input(in_sizes, n_in, TT,        used, 14);
    (void)find_input(in_sizes, n_in, 1, used, 15);                 // pred_steps
    int iSc  = find_input(in_sizes, n_in, 1,         used, 16);    // scale

    const float* inputs = (const float*)d_in[iInp];
    const float* edges  = (const float*)d_in[iEdg];
    const float* W1  = (const float*)d_in[iW1];
    const float* b1  = (const float*)d_in[ib1];
    const float* W2  = (const float*)d_in[iW2];
    const float* b2  = (const float*)d_in[ib2];
    const float* Wo1 = (const float*)d_in[iWo1];
    const float* bo1 = (const float*)d_in[ibo1];
    const float* Wo2 = (const float*)d_in[iWo2];
    const float* bo2 = (const float*)d_in[ibo2];
    const float* Wo3 = (const float*)d_in[iWo3];
    const float* bo3 = (const float*)d_in[ibo3];
    const float* ts  = (const float*)d_in[iTs];
    const void*  scp = d_in[iSc];

    char* ws = (char*)d_ws;
    _Float16* W2F  = (_Float16*)ws;                       // 262144 B
    _Float16* Wo1F = (_Float16*)(ws + 262144);            // 147456 B
    _Float16* Wo2F = (_Float16*)(ws + 409600);            // 131072 B
    float* xA  = (float*)(ws + 540672);
    float* xB  = (float*)(ws + 540672 + 1 * 32768);
    float* k1  = (float*)(ws + 540672 + 2 * 32768);
    float* k2  = (float*)(ws + 540672 + 3 * 32768);
    float* k3  = (float*)(ws + 540672 + 4 * 32768);

    float* outp = (float*)d_out;   // f32 output

    (void)hipFuncSetAttribute((const void*)stage_kernel,
        hipFuncAttributeMaxDynamicSharedMemorySize, SMEM2);

    swizzle_w2<<<dim3(512), dim3(256), 0, stream>>>(W2, W2F);
    swizzle_wo1<<<dim3(288), dim3(256), 0, stream>>>(Wo1, Wo1F);
    swizzle_wo2<<<dim3(256), dim3(256), 0, stream>>>(Wo2, Wo2F);
    init_x<<<dim3(32), dim3(256), 0, stream>>>(inputs, xA);

    float* xc = xA;
    float* xn = xB;
    for (int step = 0; step < NSTEP; ++step) {
        float* kprevs[4] = { xc, k1, k2, k3 };   // kprev per stage (xc unused at s0)
        float* kouts[4]  = { k1, k2, k3, k3 };   // kout per stage (s3 -> tail path)
        for (int s = 0; s < 4; ++s) {
            stage_kernel<<<dim3(256), dim3(512), SMEM2, stream>>>(s, step,
                edges, W1, b1, W2F, b2,
                Wo1F, bo1, Wo2F, bo2, Wo3, bo3, ts, scp, xc, kprevs[s],
                kouts[s], k1, k2, k3, xn, outp);
        }
        float* t = xc; xc = xn; xn = t;
    }
}